// Round 3
// baseline (490.817 us; speedup 1.0000x reference)
//
#include <hip/hip_runtime.h>
#include <hip/hip_bf16.h>
#include <cstdint>

// ---------------------------------------------------------------------------
// TransBlock: pre-LN transformer encoder block, bf16 MFMA compute, fp32 I/O.
// B=4 S=2048 E=1024 H=16 Dh=64 Dff=4096.  M = B*S = 8192 rows.
// ---------------------------------------------------------------------------

typedef __attribute__((ext_vector_type(8))) short bf16x8;   // 4 VGPRs, MFMA A/B frag
typedef __attribute__((ext_vector_type(4))) float f32x4;    // MFMA C/D frag

#define LDSAS __attribute__((address_space(3)))
#define GLBAS __attribute__((address_space(1)))

#define CQK 0.18033688011112044f   // (1/8) * log2(e), folded into Q at QKV epilogue

__device__ __forceinline__ unsigned short f2bf(float f) {
  union { float f; unsigned u; } c; c.f = f;
  unsigned u = c.u + 0x7fffu + ((c.u >> 16) & 1u);   // RNE
  return (unsigned short)(u >> 16);
}

__device__ __forceinline__ unsigned pk2(float a, float b) {  // v_cvt_pk path
  __hip_bfloat162 h = __float22bfloat162_rn(make_float2(a, b));
  union { __hip_bfloat162 h; unsigned u; } c; c.h = h; return c.u;
}

// async global->LDS, 16B/lane, dest = wave-uniform base + lane*16
__device__ __forceinline__ void async16(const unsigned short* g, unsigned short* l) {
  __builtin_amdgcn_global_load_lds((const GLBAS unsigned int*)g,
                                   (LDSAS unsigned int*)l, 16, 0, 0);
}

// ---------------------------------------------------------------------------
// cvt_all: all six fp32 weight arrays -> bf16 workspace in ONE launch.
// ---------------------------------------------------------------------------
__global__ void cvt_all(const float* __restrict__ q, const float* __restrict__ k,
                        const float* __restrict__ v, const float* __restrict__ o,
                        const float* __restrict__ w1, const float* __restrict__ w2,
                        unsigned short* __restrict__ wsb) {
  const long i = (long)blockIdx.x * 256 + threadIdx.x;   // float4 index
  const float* src; unsigned short* dst; long off;
  if (i < 1048576) {
    const long seg = i >> 18, o4 = i & 262143;
    src = (seg == 0) ? q : (seg == 1) ? k : (seg == 2) ? v : o;
    dst = wsb + ((seg == 3) ? 3145728L : seg * 1048576L);
    off = o4;
  } else if (i < 2097152) {
    src = w1; dst = wsb + 4194304; off = i - 1048576;
  } else {
    src = w2; dst = wsb + 8388608; off = i - 2097152;
  }
  const float4 vv = ((const float4*)src)[off];
  ushort4 r;
  r.x = f2bf(vv.x); r.y = f2bf(vv.y); r.z = f2bf(vv.z); r.w = f2bf(vv.w);
  ((ushort4*)dst)[off] = r;
}

// ---------------------------------------------------------------------------
// LayerNorm: one block per row of 1024, fp32 in -> bf16 out
// ---------------------------------------------------------------------------
__global__ void ln_fwd(const float* __restrict__ x, const float* __restrict__ g,
                       const float* __restrict__ bb, unsigned short* __restrict__ outp) {
  const int row = blockIdx.x, tid = threadIdx.x;
  const float4 v = ((const float4*)(x + (long)row * 1024))[tid];
  float s  = v.x + v.y + v.z + v.w;
  float sq = v.x * v.x + v.y * v.y + v.z * v.z + v.w * v.w;
#pragma unroll
  for (int off = 1; off < 64; off <<= 1) {
    s  += __shfl_xor(s, off);
    sq += __shfl_xor(sq, off);
  }
  __shared__ float red[8];
  const int wv = tid >> 6, lane = tid & 63;
  if (lane == 0) { red[wv] = s; red[4 + wv] = sq; }
  __syncthreads();
  s  = red[0] + red[1] + red[2] + red[3];
  sq = red[4] + red[5] + red[6] + red[7];
  const float mu  = s * (1.f / 1024.f);
  const float var = sq * (1.f / 1024.f) - mu * mu;
  const float rstd = rsqrtf(var + 1e-5f);
  const float4 gv = ((const float4*)g)[tid];
  const float4 bv = ((const float4*)bb)[tid];
  ushort4 o;
  o.x = f2bf((v.x - mu) * rstd * gv.x + bv.x);
  o.y = f2bf((v.y - mu) * rstd * gv.y + bv.y);
  o.z = f2bf((v.z - mu) * rstd * gv.z + bv.z);
  o.w = f2bf((v.w - mu) * rstd * gv.w + bv.w);
  ((ushort4*)(outp + (long)row * 1024))[tid] = o;
}

// ---------------------------------------------------------------------------
// B^T GEMM: C[M,N] = A[M,K](bf16) . B[N,K](bf16)^T
// 128x128 tile, BK=64, 256 thr = 4 waves in 2x2, per wave 4x4x2 16x16x32 MFMA.
// XOR chunk swizzle baked into async16 source columns (zero bank conflicts).
// XCD-aware block remap (m-banded per XCD). Requires gridDim.y == 64.
// EPI: 0 = store bf16; 1 = +bias +fp32 residual -> fp32; 2 = +bias, relu -> bf16
//      3 = store bf16, cols<1024 scaled by CQK
// ---------------------------------------------------------------------------
template <int EPI>
__launch_bounds__(256, 3)
__global__ void gemm_bt(const unsigned short* __restrict__ A,
                        const unsigned short* __restrict__ B,
                        void* __restrict__ Cout,
                        const float* __restrict__ bias,
                        const float* __restrict__ res,
                        int M, int N, int K) {
  __shared__ __align__(16) unsigned short As[128 * 64];   // 16 KB each
  __shared__ __align__(16) unsigned short Bs[128 * 64];
  const int tid  = threadIdx.x;
  const int lane = tid & 63;
  const int wvu  = __builtin_amdgcn_readfirstlane(tid >> 6);  // wave id, SGPR
  const int quad = lane >> 4, l16 = lane & 15;
  const int wm = wvu >> 1, wn = wvu & 1;

  const int gx = gridDim.x;
  const int id = blockIdx.y * gx + blockIdx.x;
  const int xcd = id & 7, slot = id >> 3;
  const int by = xcd * 8 + (slot & 7);
  const int bx = slot >> 3;
  const long m0 = (long)by * 128, n0 = (long)bx * 128;

  f32x4 acc[4][4];
#pragma unroll
  for (int i = 0; i < 4; i++)
#pragma unroll
    for (int j = 0; j < 4; j++) acc[i][j] = (f32x4){0.f, 0.f, 0.f, 0.f};

  const int rxA = l16 & 7;
  const int c0A = quad ^ rxA;              // kc=0 phys chunk for frag reads
  int srow[4], sgc[4];
#pragma unroll
  for (int j = 0; j < 4; ++j) {
    const int s = wvu * 256 + j * 64 + lane;
    srow[j] = s >> 3;
    sgc[j] = ((s & 7) ^ (srow[j] & 7)) * 8;
  }

  for (int k0 = 0; k0 < K; k0 += 64) {
    __syncthreads();
#pragma unroll
    for (int j = 0; j < 4; ++j) {
      const int db = (wvu * 256 + j * 64) * 8;   // wave-uniform LDS base (elems)
      async16(A + (m0 + srow[j]) * K + k0 + sgc[j], As + db);
      async16(B + (n0 + srow[j]) * K + k0 + sgc[j], Bs + db);
    }
    __syncthreads();

#pragma unroll
    for (int kc = 0; kc < 2; ++kc) {
      const int ch = (c0A ^ (kc * 4)) * 8;
      bf16x8 af[4], bfr[4];
#pragma unroll
      for (int t = 0; t < 4; ++t) {
        af[t]  = *(const bf16x8*)(As + (wm * 64 + t * 16 + l16) * 64 + ch);
        bfr[t] = *(const bf16x8*)(Bs + (wn * 64 + t * 16 + l16) * 64 + ch);
      }
#pragma unroll
      for (int mt = 0; mt < 4; ++mt)
#pragma unroll
        for (int nt = 0; nt < 4; ++nt)
          acc[mt][nt] = __builtin_amdgcn_mfma_f32_16x16x32_bf16(af[mt], bfr[nt],
                                                                acc[mt][nt], 0, 0, 0);
    }
  }

#pragma unroll
  for (int nt = 0; nt < 4; ++nt) {
    const long col = n0 + wn * 64 + nt * 16 + l16;
    float bv = 0.f;
    if (EPI == 1 || EPI == 2) bv = bias[col];
    const float scl = (EPI == 3 && col < 1024) ? CQK : 1.0f;
#pragma unroll
    for (int mt = 0; mt < 4; ++mt) {
#pragma unroll
      for (int r = 0; r < 4; ++r) {
        const long row = m0 + wm * 64 + mt * 16 + quad * 4 + r;
        const long idx = row * (long)N + col;
        float v = acc[mt][nt][r];
        if (EPI == 0) {
          ((unsigned short*)Cout)[idx] = f2bf(v);
        } else if (EPI == 1) {
          ((float*)Cout)[idx] = v + bv + res[idx];
        } else if (EPI == 2) {
          v += bv;
          ((unsigned short*)Cout)[idx] = f2bf(v > 0.f ? v : 0.f);
        } else {
          ((unsigned short*)Cout)[idx] = f2bf(v * scl);
        }
      }
    }
  }
}

// ---------------------------------------------------------------------------
// vprep: V (cols 2048.. of qkv) -> per-(b,h,kv-tile) async16-ready tiles.
// ---------------------------------------------------------------------------
__global__ void vprep(const unsigned short* __restrict__ qkv,
                      unsigned short* __restrict__ vt) {
  __shared__ unsigned short T[64 * 68];
  const int tid = threadIdx.x;           // 256
  const int t = blockIdx.x;              // kv tile 0..31
  const int bh = blockIdx.y;             // 0..63
  const int b = bh >> 4, h = bh & 15;
  const long base = ((long)b * 2048 + t * 64) * 3072 + 2048 + h * 64;
#pragma unroll
  for (int i = 0; i < 4; ++i) {
    int c = i * 256 + tid;
    int r = c >> 4, d4 = (c & 15) * 4;
    *(ushort4*)(T + r * 68 + d4) = *(const ushort4*)(qkv + base + (long)r * 3072 + d4);
  }
  __syncthreads();
  unsigned short* out = vt + ((long)bh * 32 + t) * 4096;
#pragma unroll
  for (int i = 0; i < 4; ++i) {
    int u = i * 256 + tid;               // ushort4 index 0..1023
    int c = u >> 1, half = u & 1;
    int d = c >> 3;
    int k = ((c & 7) - d) & 7;
    int kvp4 = k * 8 + half * 4;
    int sk = (kvp4 & 32) | ((kvp4 & 4) << 2) | ((kvp4 & 16) >> 1) | ((kvp4 & 8) >> 1);
    ushort4 o;
    o.x = T[(sk + 0) * 68 + d];
    o.y = T[(sk + 1) * 68 + d];
    o.z = T[(sk + 2) * 68 + d];
    o.w = T[(sk + 3) * 68 + d];
    *(ushort4*)(out + u * 4) = o;
  }
}

// ---------------------------------------------------------------------------
// Flash attention fwd, S^T formulation, fixed-base softmax.
// v3: K/V double-buffered in LDS with COUNTED vmcnt (never drain in loop).
// Q's 16 KB region is dead after bq frag reads -> aliased as the odd K buffer,
// so dbuf costs no extra LDS: 64 KB total = 2 blocks/CU (== measured occupancy
// of the old 48 KB version, so no occupancy loss).
// Per iter: compute(buf kt&1) ; barrier(reads done) ; stage(kt+2)->same buf ;
// vmcnt(8) [tile kt+1 landed, kt+2's 8 loads stay in flight] ; barrier.
// Raw s_barrier throughout -- no implicit vmcnt(0) drain (that drain was the
// old per-iter stall).  bq reads forced to registers via lgkmcnt(0) +
// sched_barrier before the K1 region is re-staged (guide rule #18).
// ---------------------------------------------------------------------------
__launch_bounds__(256, 2)
__global__ void attn_fwd(const unsigned short* __restrict__ qkv,
                         const unsigned short* __restrict__ vt,
                         unsigned short* __restrict__ outp) {
  // 64 KB: [K_even | V_even | K_odd (Q staged here first) | V_odd], 16 KB each
  __shared__ __align__(16) unsigned short lds[32768];

  const int tid = threadIdx.x;
  const int lane = tid & 63;
  const int wv = __builtin_amdgcn_readfirstlane(tid >> 6);  // 0..3
  const int quad = lane >> 4, l16 = lane & 15;

  // XCD-packed remap: xcd = id&7 owns heads [xcd*8, xcd*8+8)
  const int id = blockIdx.y * 16 + blockIdx.x;   // grid (16, 64)
  const int xcd = id & 7, slot = id >> 3;        // slot 0..127
  const int bh = xcd * 8 + (slot >> 4);
  const int qt = slot & 15;
  const int b = bh >> 4, h = bh & 15;
  const long rowbase = (long)b * 2048;
  const int hoff = h * 64;

  unsigned short* Qs = lds + 16384;   // aliases K_odd

  // ---- stage Q (128x64) via swizzled async16, 4 sets ----
  {
    const unsigned short* qsrc = qkv + (rowbase + qt * 128) * 3072 + hoff;
#pragma unroll
    for (int j = 0; j < 4; ++j) {
      const int c = j * 256 + wv * 64 + lane;
      const int row = c >> 3;
      const int k = ((c & 7) - row) & 7;
      async16(qsrc + (long)row * 3072 + k * 8, Qs + (j * 256 + wv * 64) * 8);
    }
  }
  asm volatile("s_waitcnt vmcnt(0)" ::: "memory");
  __builtin_amdgcn_s_barrier();
  __builtin_amdgcn_sched_barrier(0);

  const int rot0 = (quad + l16) & 7;
  const int rot1 = rot0 ^ 4;

  // Q B-frags: strip s covers q = wv*32 + s*16 + l16 (loop-invariant)
  bf16x8 bq[2][2];
#pragma unroll
  for (int s = 0; s < 2; ++s) {
    const int qrow = wv * 32 + s * 16 + l16;
    bq[s][0] = *(const bf16x8*)(Qs + qrow * 64 + rot0 * 8);
    bq[s][1] = *(const bf16x8*)(Qs + qrow * 64 + rot1 * 8);
  }
  asm volatile("s_waitcnt lgkmcnt(0)" ::: "memory");  // bq in regs before overwrite
  __builtin_amdgcn_sched_barrier(0);
  __builtin_amdgcn_s_barrier();                        // all waves done reading Q
  __builtin_amdgcn_sched_barrier(0);

  // staging constants (256 thr cover 1024 chunks in 4 sets)
  const int c0 = wv * 64 + lane;
  const int r0 = c0 >> 3;
  const int ks = ((c0 & 7) - r0) & 7;
  const unsigned short* kptr = qkv + (rowbase + r0) * 3072 + 1024 + hoff + ks * 8;
  const unsigned short* vptr = vt + (long)bh * 131072 + (long)c0 * 8;

  auto stage = [&](int t) {   // tile t -> buffer t&1 (8 loads/wave: 4 K + 4 V)
    unsigned short* kdst = lds + (t & 1) * 16384 + wv * 512;
    unsigned short* vdst = kdst + 8192;
    const unsigned short* kp = kptr + (long)t * 128 * 3072;
    const unsigned short* vp = vptr + (long)t * 8192;
#pragma unroll
    for (int j = 0; j < 4; ++j) {
      async16(kp + (long)j * 32 * 3072, kdst + j * 2048);
      async16(vp + j * 2048, vdst + j * 2048);
    }
  };

  bf16x8 ones;
#pragma unroll
  for (int i = 0; i < 8; ++i) ones[i] = (short)0x3F80;

  f32x4 oacc[2][4], lacc[2];
#pragma unroll
  for (int s = 0; s < 2; ++s) {
    lacc[s] = (f32x4){0.f, 0.f, 0.f, 0.f};
#pragma unroll
    for (int i = 0; i < 4; ++i) oacc[s][i] = (f32x4){0.f, 0.f, 0.f, 0.f};
  }

  // prologue: tiles 0 and 1 in flight; wait tile0 only (8 newest outstanding)
  stage(0); stage(1);
  asm volatile("s_waitcnt vmcnt(8)" ::: "memory");
  __builtin_amdgcn_s_barrier();
  __builtin_amdgcn_sched_barrier(0);

  for (int kt = 0; kt < 16; ++kt) {
    const unsigned short* Kb = lds + (kt & 1) * 16384;
    const unsigned short* Vb = Kb + 8192;

    // St = K.Q^T for both strips; ak frags shared
    f32x4 sacc[2][8];
#pragma unroll
    for (int t = 0; t < 8; ++t) {
      const int ar = t * 16 + l16;
      bf16x8 ak0 = *(const bf16x8*)(Kb + ar * 64 + rot0 * 8);
      bf16x8 ak1 = *(const bf16x8*)(Kb + ar * 64 + rot1 * 8);
#pragma unroll
      for (int s = 0; s < 2; ++s) {
        f32x4 z = (f32x4){0.f, 0.f, 0.f, 0.f};
        z = __builtin_amdgcn_mfma_f32_16x16x32_bf16(ak0, bq[s][0], z, 0, 0, 0);
        sacc[s][t] = __builtin_amdgcn_mfma_f32_16x16x32_bf16(ak1, bq[s][1], z, 0, 0, 0);
      }
    }

    // fixed-base softmax: p = exp2(s); pack to A-frags; l via ones-MFMA
    union APU { unsigned u[4]; bf16x8 v; } ap[2][4];
#pragma unroll
    for (int s = 0; s < 2; ++s)
#pragma unroll
      for (int hf = 0; hf < 4; ++hf) {
#pragma unroll
        for (int t = 0; t < 2; ++t) {
          const f32x4 sv = sacc[s][hf * 2 + t];
          const float p0 = __builtin_amdgcn_exp2f(sv[0]);
          const float p1 = __builtin_amdgcn_exp2f(sv[1]);
          const float p2 = __builtin_amdgcn_exp2f(sv[2]);
          const float p3 = __builtin_amdgcn_exp2f(sv[3]);
          ap[s][hf].u[t * 2 + 0] = pk2(p0, p1);
          ap[s][hf].u[t * 2 + 1] = pk2(p2, p3);
        }
        lacc[s] = __builtin_amdgcn_mfma_f32_16x16x32_bf16(ap[s][hf].v, ones,
                                                          lacc[s], 0, 0, 0);
      }

    // O += P.V : bv frags shared across both strips
#pragma unroll
    for (int hf = 0; hf < 4; ++hf) {
      const int vbase = (hf >> 1) * 4096 + ((hf & 1) ? rot1 : rot0) * 8;
#pragma unroll
      for (int dt = 0; dt < 4; ++dt) {
        bf16x8 bv = *(const bf16x8*)(Vb + vbase + (dt * 16 + l16) * 64);
#pragma unroll
        for (int s = 0; s < 2; ++s)
          oacc[s][dt] = __builtin_amdgcn_mfma_f32_16x16x32_bf16(ap[s][hf].v, bv,
                                                                oacc[s][dt], 0, 0, 0);
      }
    }

    if (kt == 15) break;
    // all LDS reads above are consumed by MFMAs (lgkm waited) before here
    __builtin_amdgcn_s_barrier();          // all waves done reading buf(kt&1)
    __builtin_amdgcn_sched_barrier(0);
    if (kt + 2 < 16) {
      stage(kt + 2);                       // overwrite just-read buffer
      asm volatile("s_waitcnt vmcnt(8)" ::: "memory");   // tile kt+1 landed
    } else {
      asm volatile("s_waitcnt vmcnt(0)" ::: "memory");   // last tile: drain once
    }
    __builtin_amdgcn_s_barrier();          // tile kt+1 visible to all waves
    __builtin_amdgcn_sched_barrier(0);
  }

  // epilogue: q-row = wv*32 + s*16 + quad*4 + r; lacc already in that layout
#pragma unroll
  for (int s = 0; s < 2; ++s) {
    float linv[4];
#pragma unroll
    for (int r = 0; r < 4; ++r) linv[r] = 1.f / lacc[s][r];
#pragma unroll
    for (int dt = 0; dt < 4; ++dt)
#pragma unroll
      for (int r = 0; r < 4; ++r) {
        const long row = rowbase + qt * 128 + wv * 32 + s * 16 + quad * 4 + r;
        outp[row * 1024 + hoff + dt * 16 + l16] = f2bf(oacc[s][dt][r] * linv[r]);
      }
  }
}

// ---------------------------------------------------------------------------
// launch
// ---------------------------------------------------------------------------
extern "C" void kernel_launch(void* const* d_in, const int* in_sizes, int n_in,
                              void* d_out, int out_size, void* d_ws, size_t ws_size,
                              hipStream_t stream) {
  (void)in_sizes; (void)n_in; (void)out_size; (void)ws_size;
  const float* x   = (const float*)d_in[0];
  const float* Wq  = (const float*)d_in[1];
  const float* Wk  = (const float*)d_in[2];
  const float* Wv  = (const float*)d_in[3];
  const float* Wo  = (const float*)d_in[4];
  const float* bo  = (const float*)d_in[5];
  const float* g1  = (const float*)d_in[6];
  const float* be1 = (const float*)d_in[7];
  const float* g2  = (const float*)d_in[8];
  const float* be2 = (const float*)d_in[9];
  const float* W1  = (const float*)d_in[10];
  const float* bf1 = (const float*)d_in[11];
  const float* W2  = (const float*)d_in[12];
  const float* bf2 = (const float*)d_in[13];

  char* ws = (char*)d_ws;
  unsigned short* wqkv  = (unsigned short*)(ws);              // [3072,1024] bf16   6 MiB
  unsigned short* wo    = (unsigned short*)(ws + 6291456);    // [1024,1024]        2 MiB
  unsigned short* w1    = (unsigned short*)(ws + 8388608);    // [4096,1024]        8 MiB
  unsigned short* w2    = (unsigned short*)(ws + 16777216);   // [1024,4096]        8 MiB
  unsigned short* xn    = (unsigned short*)(ws + 25165824);   // [8192,1024]       16 MiB
  unsigned short* big   = (unsigned short*)(ws + 41943040);   // qkv/h             64 MiB
  unsigned short* attnb = (unsigned short*)(ws + 109051904);  // [8192,1024]       16 MiB
  float*          x1    = (float*)(ws + 125829120);           // [8192,1024] f32   32 MiB
  // vtg aliases xn: LN1's xn dead after QKV GEMM; attn consumes before LN2.
  unsigned short* vtg   = xn;                                 // [64][32][4096]    16 MiB

  cvt_all<<<12288, 256, 0, stream>>>(Wq, Wk, Wv, Wo, W1, W2, wqkv);

  ln_fwd<<<8192, 256, 0, stream>>>(x, g1, be1, xn);
  gemm_bt<3><<<dim3(24, 64), 256, 0, stream>>>(xn, wqkv, big, nullptr, nullptr,
                                               8192, 3072, 1024);
  vprep<<<dim3(32, 64), 256, 0, stream>>>(big, vtg);
  attn_fwd<<<dim3(16, 64), 256, 0, stream>>>(big, vtg, attnb);
  gemm_bt<1><<<dim3(8, 64), 256, 0, stream>>>(attnb, wo, x1, bo, x,
                                              8192, 1024, 1024);
  ln_fwd<<<8192, 256, 0, stream>>>(x1, g2, be2, xn);
  gemm_bt<2><<<dim3(32, 64), 256, 0, stream>>>(xn, w1, big, bf1, nullptr,
                                               8192, 4096, 1024);
  gemm_bt<1><<<dim3(8, 64), 256, 0, stream>>>(big, w2, (float*)d_out, bf2, x1,
                                              8192, 1024, 4096);
}

// Round 4
// 485.309 us; speedup vs baseline: 1.0113x; 1.0113x over previous
//
#include <hip/hip_runtime.h>
#include <hip/hip_bf16.h>
#include <cstdint>

// ---------------------------------------------------------------------------
// TransBlock: pre-LN transformer encoder block, bf16 MFMA compute, fp32 I/O.
// B=4 S=2048 E=1024 H=16 Dh=64 Dff=4096.  M = B*S = 8192 rows.
// ---------------------------------------------------------------------------

typedef __attribute__((ext_vector_type(8))) short bf16x8;   // 4 VGPRs, MFMA A/B frag
typedef __attribute__((ext_vector_type(4))) float f32x4;    // MFMA C/D frag

#define LDSAS __attribute__((address_space(3)))
#define GLBAS __attribute__((address_space(1)))

#define CQK 0.18033688011112044f   // (1/8) * log2(e), folded into Q at QKV epilogue

__device__ __forceinline__ unsigned short f2bf(float f) {
  union { float f; unsigned u; } c; c.f = f;
  unsigned u = c.u + 0x7fffu + ((c.u >> 16) & 1u);   // RNE
  return (unsigned short)(u >> 16);
}

__device__ __forceinline__ unsigned pk2(float a, float b) {  // v_cvt_pk path
  __hip_bfloat162 h = __float22bfloat162_rn(make_float2(a, b));
  union { __hip_bfloat162 h; unsigned u; } c; c.h = h; return c.u;
}

// async global->LDS, 16B/lane, dest = wave-uniform base + lane*16
__device__ __forceinline__ void async16(const unsigned short* g, unsigned short* l) {
  __builtin_amdgcn_global_load_lds((const GLBAS unsigned int*)g,
                                   (LDSAS unsigned int*)l, 16, 0, 0);
}

// ---------------------------------------------------------------------------
// cvt_all: all six fp32 weight arrays -> bf16 workspace in ONE launch.
// ---------------------------------------------------------------------------
__global__ void cvt_all(const float* __restrict__ q, const float* __restrict__ k,
                        const float* __restrict__ v, const float* __restrict__ o,
                        const float* __restrict__ w1, const float* __restrict__ w2,
                        unsigned short* __restrict__ wsb) {
  const long i = (long)blockIdx.x * 256 + threadIdx.x;   // float4 index
  const float* src; unsigned short* dst; long off;
  if (i < 1048576) {
    const long seg = i >> 18, o4 = i & 262143;
    src = (seg == 0) ? q : (seg == 1) ? k : (seg == 2) ? v : o;
    dst = wsb + ((seg == 3) ? 3145728L : seg * 1048576L);
    off = o4;
  } else if (i < 2097152) {
    src = w1; dst = wsb + 4194304; off = i - 1048576;
  } else {
    src = w2; dst = wsb + 8388608; off = i - 2097152;
  }
  const float4 vv = ((const float4*)src)[off];
  ushort4 r;
  r.x = f2bf(vv.x); r.y = f2bf(vv.y); r.z = f2bf(vv.z); r.w = f2bf(vv.w);
  ((ushort4*)dst)[off] = r;
}

// ---------------------------------------------------------------------------
// LayerNorm: one block per row of 1024, fp32 in -> bf16 out
// ---------------------------------------------------------------------------
__global__ void ln_fwd(const float* __restrict__ x, const float* __restrict__ g,
                       const float* __restrict__ bb, unsigned short* __restrict__ outp) {
  const int row = blockIdx.x, tid = threadIdx.x;
  const float4 v = ((const float4*)(x + (long)row * 1024))[tid];
  float s  = v.x + v.y + v.z + v.w;
  float sq = v.x * v.x + v.y * v.y + v.z * v.z + v.w * v.w;
#pragma unroll
  for (int off = 1; off < 64; off <<= 1) {
    s  += __shfl_xor(s, off);
    sq += __shfl_xor(sq, off);
  }
  __shared__ float red[8];
  const int wv = tid >> 6, lane = tid & 63;
  if (lane == 0) { red[wv] = s; red[4 + wv] = sq; }
  __syncthreads();
  s  = red[0] + red[1] + red[2] + red[3];
  sq = red[4] + red[5] + red[6] + red[7];
  const float mu  = s * (1.f / 1024.f);
  const float var = sq * (1.f / 1024.f) - mu * mu;
  const float rstd = rsqrtf(var + 1e-5f);
  const float4 gv = ((const float4*)g)[tid];
  const float4 bv = ((const float4*)bb)[tid];
  ushort4 o;
  o.x = f2bf((v.x - mu) * rstd * gv.x + bv.x);
  o.y = f2bf((v.y - mu) * rstd * gv.y + bv.y);
  o.z = f2bf((v.z - mu) * rstd * gv.z + bv.z);
  o.w = f2bf((v.w - mu) * rstd * gv.w + bv.w);
  ((ushort4*)(outp + (long)row * 1024))[tid] = o;
}

// ---------------------------------------------------------------------------
// B^T GEMM: C[M,N] = A[M,K](bf16) . B[N,K](bf16)^T
// 128x128 tile, BK=64, 256 thr = 4 waves in 2x2, per wave 4x4x2 16x16x32 MFMA.
// XOR chunk swizzle baked into async16 source columns (zero bank conflicts).
// XCD-aware block remap (m-banded per XCD). Requires gridDim.y == 64.
// EPI: 0 = store bf16; 1 = +bias +fp32 residual -> fp32; 2 = +bias, relu -> bf16
//      3 = store bf16, cols<1024 scaled by CQK
// ---------------------------------------------------------------------------
template <int EPI>
__launch_bounds__(256, 3)
__global__ void gemm_bt(const unsigned short* __restrict__ A,
                        const unsigned short* __restrict__ B,
                        void* __restrict__ Cout,
                        const float* __restrict__ bias,
                        const float* __restrict__ res,
                        int M, int N, int K) {
  __shared__ __align__(16) unsigned short As[128 * 64];   // 16 KB each
  __shared__ __align__(16) unsigned short Bs[128 * 64];
  const int tid  = threadIdx.x;
  const int lane = tid & 63;
  const int wvu  = __builtin_amdgcn_readfirstlane(tid >> 6);  // wave id, SGPR
  const int quad = lane >> 4, l16 = lane & 15;
  const int wm = wvu >> 1, wn = wvu & 1;

  const int gx = gridDim.x;
  const int id = blockIdx.y * gx + blockIdx.x;
  const int xcd = id & 7, slot = id >> 3;
  const int by = xcd * 8 + (slot & 7);
  const int bx = slot >> 3;
  const long m0 = (long)by * 128, n0 = (long)bx * 128;

  f32x4 acc[4][4];
#pragma unroll
  for (int i = 0; i < 4; i++)
#pragma unroll
    for (int j = 0; j < 4; j++) acc[i][j] = (f32x4){0.f, 0.f, 0.f, 0.f};

  const int rxA = l16 & 7;
  const int c0A = quad ^ rxA;              // kc=0 phys chunk for frag reads
  int srow[4], sgc[4];
#pragma unroll
  for (int j = 0; j < 4; ++j) {
    const int s = wvu * 256 + j * 64 + lane;
    srow[j] = s >> 3;
    sgc[j] = ((s & 7) ^ (srow[j] & 7)) * 8;
  }

  for (int k0 = 0; k0 < K; k0 += 64) {
    __syncthreads();
#pragma unroll
    for (int j = 0; j < 4; ++j) {
      const int db = (wvu * 256 + j * 64) * 8;   // wave-uniform LDS base (elems)
      async16(A + (m0 + srow[j]) * K + k0 + sgc[j], As + db);
      async16(B + (n0 + srow[j]) * K + k0 + sgc[j], Bs + db);
    }
    __syncthreads();

#pragma unroll
    for (int kc = 0; kc < 2; ++kc) {
      const int ch = (c0A ^ (kc * 4)) * 8;
      bf16x8 af[4], bfr[4];
#pragma unroll
      for (int t = 0; t < 4; ++t) {
        af[t]  = *(const bf16x8*)(As + (wm * 64 + t * 16 + l16) * 64 + ch);
        bfr[t] = *(const bf16x8*)(Bs + (wn * 64 + t * 16 + l16) * 64 + ch);
      }
#pragma unroll
      for (int mt = 0; mt < 4; ++mt)
#pragma unroll
        for (int nt = 0; nt < 4; ++nt)
          acc[mt][nt] = __builtin_amdgcn_mfma_f32_16x16x32_bf16(af[mt], bfr[nt],
                                                                acc[mt][nt], 0, 0, 0);
    }
  }

#pragma unroll
  for (int nt = 0; nt < 4; ++nt) {
    const long col = n0 + wn * 64 + nt * 16 + l16;
    float bv = 0.f;
    if (EPI == 1 || EPI == 2) bv = bias[col];
    const float scl = (EPI == 3 && col < 1024) ? CQK : 1.0f;
#pragma unroll
    for (int mt = 0; mt < 4; ++mt) {
#pragma unroll
      for (int r = 0; r < 4; ++r) {
        const long row = m0 + wm * 64 + mt * 16 + quad * 4 + r;
        const long idx = row * (long)N + col;
        float v = acc[mt][nt][r];
        if (EPI == 0) {
          ((unsigned short*)Cout)[idx] = f2bf(v);
        } else if (EPI == 1) {
          ((float*)Cout)[idx] = v + bv + res[idx];
        } else if (EPI == 2) {
          v += bv;
          ((unsigned short*)Cout)[idx] = f2bf(v > 0.f ? v : 0.f);
        } else {
          ((unsigned short*)Cout)[idx] = f2bf(v * scl);
        }
      }
    }
  }
}

// ---------------------------------------------------------------------------
// vprep: V (cols 2048.. of qkv) -> per-(b,h,kv-tile) async16-ready tiles.
// ---------------------------------------------------------------------------
__global__ void vprep(const unsigned short* __restrict__ qkv,
                      unsigned short* __restrict__ vt) {
  __shared__ unsigned short T[64 * 68];
  const int tid = threadIdx.x;           // 256
  const int t = blockIdx.x;              // kv tile 0..31
  const int bh = blockIdx.y;             // 0..63
  const int b = bh >> 4, h = bh & 15;
  const long base = ((long)b * 2048 + t * 64) * 3072 + 2048 + h * 64;
#pragma unroll
  for (int i = 0; i < 4; ++i) {
    int c = i * 256 + tid;
    int r = c >> 4, d4 = (c & 15) * 4;
    *(ushort4*)(T + r * 68 + d4) = *(const ushort4*)(qkv + base + (long)r * 3072 + d4);
  }
  __syncthreads();
  unsigned short* out = vt + ((long)bh * 32 + t) * 4096;
#pragma unroll
  for (int i = 0; i < 4; ++i) {
    int u = i * 256 + tid;               // ushort4 index 0..1023
    int c = u >> 1, half = u & 1;
    int d = c >> 3;
    int k = ((c & 7) - d) & 7;
    int kvp4 = k * 8 + half * 4;
    int sk = (kvp4 & 32) | ((kvp4 & 4) << 2) | ((kvp4 & 16) >> 1) | ((kvp4 & 8) >> 1);
    ushort4 o;
    o.x = T[(sk + 0) * 68 + d];
    o.y = T[(sk + 1) * 68 + d];
    o.z = T[(sk + 2) * 68 + d];
    o.w = T[(sk + 3) * 68 + d];
    *(ushort4*)(out + u * 4) = o;
  }
}

// ---------------------------------------------------------------------------
// Flash attention fwd, S^T formulation, fixed-base softmax.
// v4: occupancy-driven.  VALU-bound softmax (VALUBusy 46% at 2 blocks/CU)
// needs more resident waves to pack the VALU pipe, so:
//  - Q loaded DIRECTLY to registers (swizzle algebra: lane (quad,l16) reads
//    global chunks quad / quad^4 of its q-rows) -> no Q LDS.
//  - KVBLK=64 (1 vt tile per iter): K/V dbuf = 4 x 8 KB = 32 KB LDS total
//    -> 4 blocks/CU co-resident (grid 1024 = exactly 4/CU, single round).
//  - counted vmcnt(4) steady state (4 loads/tile), raw s_barriers, never
//    drain in loop (kept from v3, which measured -6%).
//  - T5 setprio(1) around QK and PV MFMA clusters (independent blocks per
//    CU at different phases = m191's positive regime).
// ---------------------------------------------------------------------------
__launch_bounds__(256, 4)
__global__ void attn_fwd(const unsigned short* __restrict__ qkv,
                         const unsigned short* __restrict__ vt,
                         unsigned short* __restrict__ outp) {
  // 32 KB: [K0 | K1 | V0 | V1], 8 KB (4096 ushorts) each
  __shared__ __align__(16) unsigned short lds[16384];

  const int tid = threadIdx.x;
  const int lane = tid & 63;
  const int wv = __builtin_amdgcn_readfirstlane(tid >> 6);  // 0..3
  const int quad = lane >> 4, l16 = lane & 15;

  // XCD-packed remap: xcd = id&7 owns heads [xcd*8, xcd*8+8)
  const int id = blockIdx.y * 16 + blockIdx.x;   // grid (16, 64)
  const int xcd = id & 7, slot = id >> 3;        // slot 0..127
  const int bh = xcd * 8 + (slot >> 4);
  const int qt = slot & 15;
  const int b = bh >> 4, h = bh & 15;
  const long rowbase = (long)b * 2048;
  const int hoff = h * 64;

  const int rot0 = (quad + l16) & 7;
  const int rot1 = rot0 ^ 4;

  // ---- Q direct to registers (4 x 16B loads, one-time) ----
  bf16x8 bq[2][2];
#pragma unroll
  for (int s = 0; s < 2; ++s) {
    const long qrow = rowbase + qt * 128 + wv * 32 + s * 16 + l16;
    const unsigned short* qp = qkv + qrow * 3072 + hoff;
    bq[s][0] = *(const bf16x8*)(qp + quad * 8);
    bq[s][1] = *(const bf16x8*)(qp + (quad ^ 4) * 8);
  }
  __builtin_amdgcn_sched_barrier(0);   // keep bq loads issued before staging

  // staging constants: 512 chunks per 64-kv tile, 2 sets of 256
  const int c0 = wv * 64 + lane;          // chunk 0..255
  const int r0 = c0 >> 3;                 // row 0..31
  const int ks = ((c0 & 7) - r0) & 7;
  const unsigned short* kptr = qkv + (rowbase + r0) * 3072 + 1024 + hoff + ks * 8;
  const unsigned short* vptr = vt + (long)bh * 131072 + (long)c0 * 8;

  auto stage = [&](int t) {   // 64-kv tile t -> buffers t&1 (4 loads/wave)
    unsigned short* kdst = lds + (t & 1) * 4096 + wv * 512;
    unsigned short* vdst = lds + 8192 + (t & 1) * 4096 + wv * 512;
    const unsigned short* kp = kptr + (long)t * 64 * 3072;
    const unsigned short* vp = vptr + (long)t * 4096;
#pragma unroll
    for (int j = 0; j < 2; ++j) {
      async16(kp + (long)j * 32 * 3072, kdst + j * 2048);
      async16(vp + j * 2048, vdst + j * 2048);
    }
  };

  bf16x8 ones;
#pragma unroll
  for (int i = 0; i < 8; ++i) ones[i] = (short)0x3F80;

  f32x4 oacc[2][4], lacc[2];
#pragma unroll
  for (int s = 0; s < 2; ++s) {
    lacc[s] = (f32x4){0.f, 0.f, 0.f, 0.f};
#pragma unroll
    for (int i = 0; i < 4; ++i) oacc[s][i] = (f32x4){0.f, 0.f, 0.f, 0.f};
  }

  // prologue: bq(4) + tile0(4) + tile1(4) outstanding; vmcnt(4) -> bq+tile0 done
  stage(0); stage(1);
  asm volatile("s_waitcnt vmcnt(4)" ::: "memory");
  __builtin_amdgcn_s_barrier();
  __builtin_amdgcn_sched_barrier(0);

  for (int kt = 0; kt < 32; ++kt) {
    const unsigned short* Kb = lds + (kt & 1) * 4096;
    const unsigned short* Vb = lds + 8192 + (kt & 1) * 4096;

    // St = K.Q^T for both strips; ak frags shared
    f32x4 sacc[2][4];
    __builtin_amdgcn_s_setprio(1);
#pragma unroll
    for (int t = 0; t < 4; ++t) {
      const int ar = t * 16 + l16;
      bf16x8 ak0 = *(const bf16x8*)(Kb + ar * 64 + rot0 * 8);
      bf16x8 ak1 = *(const bf16x8*)(Kb + ar * 64 + rot1 * 8);
#pragma unroll
      for (int s = 0; s < 2; ++s) {
        f32x4 z = (f32x4){0.f, 0.f, 0.f, 0.f};
        z = __builtin_amdgcn_mfma_f32_16x16x32_bf16(ak0, bq[s][0], z, 0, 0, 0);
        sacc[s][t] = __builtin_amdgcn_mfma_f32_16x16x32_bf16(ak1, bq[s][1], z, 0, 0, 0);
      }
    }
    __builtin_amdgcn_s_setprio(0);

    // fixed-base softmax: p = exp2(s); pack to A-frags; l via ones-MFMA
    union APU { unsigned u[4]; bf16x8 v; } ap[2][2];
#pragma unroll
    for (int s = 0; s < 2; ++s)
#pragma unroll
      for (int hf = 0; hf < 2; ++hf) {
#pragma unroll
        for (int t = 0; t < 2; ++t) {
          const f32x4 sv = sacc[s][hf * 2 + t];
          const float p0 = __builtin_amdgcn_exp2f(sv[0]);
          const float p1 = __builtin_amdgcn_exp2f(sv[1]);
          const float p2 = __builtin_amdgcn_exp2f(sv[2]);
          const float p3 = __builtin_amdgcn_exp2f(sv[3]);
          ap[s][hf].u[t * 2 + 0] = pk2(p0, p1);
          ap[s][hf].u[t * 2 + 1] = pk2(p2, p3);
        }
        lacc[s] = __builtin_amdgcn_mfma_f32_16x16x32_bf16(ap[s][hf].v, ones,
                                                          lacc[s], 0, 0, 0);
      }

    // O += P.V : bv frags shared across both strips
    __builtin_amdgcn_s_setprio(1);
#pragma unroll
    for (int hf = 0; hf < 2; ++hf) {
      const int vbase = (hf ? rot1 : rot0) * 8;
#pragma unroll
      for (int dt = 0; dt < 4; ++dt) {
        bf16x8 bv = *(const bf16x8*)(Vb + vbase + (dt * 16 + l16) * 64);
#pragma unroll
        for (int s = 0; s < 2; ++s)
          oacc[s][dt] = __builtin_amdgcn_mfma_f32_16x16x32_bf16(ap[s][hf].v, bv,
                                                                oacc[s][dt], 0, 0, 0);
      }
    }
    __builtin_amdgcn_s_setprio(0);

    if (kt == 31) break;
    // LDS reads above completed (lgkm waited before dependent MFMAs issued)
    __builtin_amdgcn_s_barrier();          // all waves done reading buf(kt&1)
    __builtin_amdgcn_sched_barrier(0);
    if (kt + 2 < 32) {
      stage(kt + 2);                       // overwrite just-read buffer
      asm volatile("s_waitcnt vmcnt(4)" ::: "memory");   // tile kt+1 landed
    } else {
      asm volatile("s_waitcnt vmcnt(0)" ::: "memory");   // last tile: drain once
    }
    __builtin_amdgcn_s_barrier();          // tile kt+1 visible to all waves
    __builtin_amdgcn_sched_barrier(0);
  }

  // epilogue: q-row = wv*32 + s*16 + quad*4 + r; lacc already in that layout
#pragma unroll
  for (int s = 0; s < 2; ++s) {
    float linv[4];
#pragma unroll
    for (int r = 0; r < 4; ++r) linv[r] = 1.f / lacc[s][r];
#pragma unroll
    for (int dt = 0; dt < 4; ++dt)
#pragma unroll
      for (int r = 0; r < 4; ++r) {
        const long row = rowbase + qt * 128 + wv * 32 + s * 16 + quad * 4 + r;
        outp[row * 1024 + hoff + dt * 16 + l16] = f2bf(oacc[s][dt][r] * linv[r]);
      }
  }
}

// ---------------------------------------------------------------------------
// launch
// ---------------------------------------------------------------------------
extern "C" void kernel_launch(void* const* d_in, const int* in_sizes, int n_in,
                              void* d_out, int out_size, void* d_ws, size_t ws_size,
                              hipStream_t stream) {
  (void)in_sizes; (void)n_in; (void)out_size; (void)ws_size;
  const float* x   = (const float*)d_in[0];
  const float* Wq  = (const float*)d_in[1];
  const float* Wk  = (const float*)d_in[2];
  const float* Wv  = (const float*)d_in[3];
  const float* Wo  = (const float*)d_in[4];
  const float* bo  = (const float*)d_in[5];
  const float* g1  = (const float*)d_in[6];
  const float* be1 = (const float*)d_in[7];
  const float* g2  = (const float*)d_in[8];
  const float* be2 = (const float*)d_in[9];
  const float* W1  = (const float*)d_in[10];
  const float* bf1 = (const float*)d_in[11];
  const float* W2  = (const float*)d_in[12];
  const float* bf2 = (const float*)d_in[13];

  char* ws = (char*)d_ws;
  unsigned short* wqkv  = (unsigned short*)(ws);              // [3072,1024] bf16   6 MiB
  unsigned short* wo    = (unsigned short*)(ws + 6291456);    // [1024,1024]        2 MiB
  unsigned short* w1    = (unsigned short*)(ws + 8388608);    // [4096,1024]        8 MiB
  unsigned short* w2    = (unsigned short*)(ws + 16777216);   // [1024,4096]        8 MiB
  unsigned short* xn    = (unsigned short*)(ws + 25165824);   // [8192,1024]       16 MiB
  unsigned short* big   = (unsigned short*)(ws + 41943040);   // qkv/h             64 MiB
  unsigned short* attnb = (unsigned short*)(ws + 109051904);  // [8192,1024]       16 MiB
  float*          x1    = (float*)(ws + 125829120);           // [8192,1024] f32   32 MiB
  // vtg aliases xn: LN1's xn dead after QKV GEMM; attn consumes before LN2.
  unsigned short* vtg   = xn;                                 // [64][32][4096]    16 MiB

  cvt_all<<<12288, 256, 0, stream>>>(Wq, Wk, Wv, Wo, W1, W2, wqkv);

  ln_fwd<<<8192, 256, 0, stream>>>(x, g1, be1, xn);
  gemm_bt<3><<<dim3(24, 64), 256, 0, stream>>>(xn, wqkv, big, nullptr, nullptr,
                                               8192, 3072, 1024);
  vprep<<<dim3(32, 64), 256, 0, stream>>>(big, vtg);
  attn_fwd<<<dim3(16, 64), 256, 0, stream>>>(big, vtg, attnb);
  gemm_bt<1><<<dim3(8, 64), 256, 0, stream>>>(attnb, wo, x1, bo, x,
                                              8192, 1024, 1024);
  ln_fwd<<<8192, 256, 0, stream>>>(x1, g2, be2, xn);
  gemm_bt<2><<<dim3(32, 64), 256, 0, stream>>>(xn, w1, big, bf1, nullptr,
                                               8192, 4096, 1024);
  gemm_bt<1><<<dim3(8, 64), 256, 0, stream>>>(big, w2, (float*)d_out, bf2, x1,
                                              8192, 1024, 4096);
}

// Round 5
// 474.755 us; speedup vs baseline: 1.0338x; 1.0222x over previous
//
#include <hip/hip_runtime.h>
#include <hip/hip_bf16.h>
#include <cstdint>

// ---------------------------------------------------------------------------
// TransBlock: pre-LN transformer encoder block, bf16 MFMA compute, fp32 I/O.
// B=4 S=2048 E=1024 H=16 Dh=64 Dff=4096.  M = B*S = 8192 rows.
// ---------------------------------------------------------------------------

typedef __attribute__((ext_vector_type(8))) short bf16x8;   // 4 VGPRs, MFMA A/B frag
typedef __attribute__((ext_vector_type(4))) float f32x4;    // MFMA C/D frag

#define LDSAS __attribute__((address_space(3)))
#define GLBAS __attribute__((address_space(1)))

#define CQK 0.18033688011112044f   // (1/8) * log2(e), folded into Q at QKV epilogue

__device__ __forceinline__ unsigned short f2bf(float f) {
  union { float f; unsigned u; } c; c.f = f;
  unsigned u = c.u + 0x7fffu + ((c.u >> 16) & 1u);   // RNE
  return (unsigned short)(u >> 16);
}

__device__ __forceinline__ unsigned pk2(float a, float b) {  // v_cvt_pk path
  __hip_bfloat162 h = __float22bfloat162_rn(make_float2(a, b));
  union { __hip_bfloat162 h; unsigned u; } c; c.h = h; return c.u;
}

// async global->LDS, 16B/lane, dest = wave-uniform base + lane*16
__device__ __forceinline__ void async16(const unsigned short* g, unsigned short* l) {
  __builtin_amdgcn_global_load_lds((const GLBAS unsigned int*)g,
                                   (LDSAS unsigned int*)l, 16, 0, 0);
}

// ---------------------------------------------------------------------------
// cvt_all: all six fp32 weight arrays -> bf16 workspace in ONE launch.
// ---------------------------------------------------------------------------
__global__ void cvt_all(const float* __restrict__ q, const float* __restrict__ k,
                        const float* __restrict__ v, const float* __restrict__ o,
                        const float* __restrict__ w1, const float* __restrict__ w2,
                        unsigned short* __restrict__ wsb) {
  const long i = (long)blockIdx.x * 256 + threadIdx.x;   // float4 index
  const float* src; unsigned short* dst; long off;
  if (i < 1048576) {
    const long seg = i >> 18, o4 = i & 262143;
    src = (seg == 0) ? q : (seg == 1) ? k : (seg == 2) ? v : o;
    dst = wsb + ((seg == 3) ? 3145728L : seg * 1048576L);
    off = o4;
  } else if (i < 2097152) {
    src = w1; dst = wsb + 4194304; off = i - 1048576;
  } else {
    src = w2; dst = wsb + 8388608; off = i - 2097152;
  }
  const float4 vv = ((const float4*)src)[off];
  ushort4 r;
  r.x = f2bf(vv.x); r.y = f2bf(vv.y); r.z = f2bf(vv.z); r.w = f2bf(vv.w);
  ((ushort4*)dst)[off] = r;
}

// ---------------------------------------------------------------------------
// LayerNorm: one block per row of 1024, fp32 in -> bf16 out
// ---------------------------------------------------------------------------
__global__ void ln_fwd(const float* __restrict__ x, const float* __restrict__ g,
                       const float* __restrict__ bb, unsigned short* __restrict__ outp) {
  const int row = blockIdx.x, tid = threadIdx.x;
  const float4 v = ((const float4*)(x + (long)row * 1024))[tid];
  float s  = v.x + v.y + v.z + v.w;
  float sq = v.x * v.x + v.y * v.y + v.z * v.z + v.w * v.w;
#pragma unroll
  for (int off = 1; off < 64; off <<= 1) {
    s  += __shfl_xor(s, off);
    sq += __shfl_xor(sq, off);
  }
  __shared__ float red[8];
  const int wv = tid >> 6, lane = tid & 63;
  if (lane == 0) { red[wv] = s; red[4 + wv] = sq; }
  __syncthreads();
  s  = red[0] + red[1] + red[2] + red[3];
  sq = red[4] + red[5] + red[6] + red[7];
  const float mu  = s * (1.f / 1024.f);
  const float var = sq * (1.f / 1024.f) - mu * mu;
  const float rstd = rsqrtf(var + 1e-5f);
  const float4 gv = ((const float4*)g)[tid];
  const float4 bv = ((const float4*)bb)[tid];
  ushort4 o;
  o.x = f2bf((v.x - mu) * rstd * gv.x + bv.x);
  o.y = f2bf((v.y - mu) * rstd * gv.y + bv.y);
  o.z = f2bf((v.z - mu) * rstd * gv.z + bv.z);
  o.w = f2bf((v.w - mu) * rstd * gv.w + bv.w);
  ((ushort4*)(outp + (long)row * 1024))[tid] = o;
}

// ---------------------------------------------------------------------------
// B^T GEMM: C[M,N] = A[M,K](bf16) . B[N,K](bf16)^T
// 128x128 tile, BK=64, 256 thr = 4 waves in 2x2, per wave 4x4x2 16x16x32 MFMA.
// Used for K=1024 GEMMs (QKV, Wo, W1) where the deep pipeline can't fill.
// EPI: 0 = store bf16; 1 = +bias +fp32 residual -> fp32; 2 = +bias, relu -> bf16
//      3 = store bf16, cols<1024 scaled by CQK
// ---------------------------------------------------------------------------
template <int EPI>
__launch_bounds__(256, 3)
__global__ void gemm_bt(const unsigned short* __restrict__ A,
                        const unsigned short* __restrict__ B,
                        void* __restrict__ Cout,
                        const float* __restrict__ bias,
                        const float* __restrict__ res,
                        int M, int N, int K) {
  __shared__ __align__(16) unsigned short As[128 * 64];   // 16 KB each
  __shared__ __align__(16) unsigned short Bs[128 * 64];
  const int tid  = threadIdx.x;
  const int lane = tid & 63;
  const int wvu  = __builtin_amdgcn_readfirstlane(tid >> 6);  // wave id, SGPR
  const int quad = lane >> 4, l16 = lane & 15;
  const int wm = wvu >> 1, wn = wvu & 1;

  const int gx = gridDim.x;
  const int id = blockIdx.y * gx + blockIdx.x;
  const int xcd = id & 7, slot = id >> 3;
  const int by = xcd * 8 + (slot & 7);
  const int bx = slot >> 3;
  const long m0 = (long)by * 128, n0 = (long)bx * 128;

  f32x4 acc[4][4];
#pragma unroll
  for (int i = 0; i < 4; i++)
#pragma unroll
    for (int j = 0; j < 4; j++) acc[i][j] = (f32x4){0.f, 0.f, 0.f, 0.f};

  const int rxA = l16 & 7;
  const int c0A = quad ^ rxA;              // kc=0 phys chunk for frag reads
  int srow[4], sgc[4];
#pragma unroll
  for (int j = 0; j < 4; ++j) {
    const int s = wvu * 256 + j * 64 + lane;
    srow[j] = s >> 3;
    sgc[j] = ((s & 7) ^ (srow[j] & 7)) * 8;
  }

  for (int k0 = 0; k0 < K; k0 += 64) {
    __syncthreads();
#pragma unroll
    for (int j = 0; j < 4; ++j) {
      const int db = (wvu * 256 + j * 64) * 8;   // wave-uniform LDS base (elems)
      async16(A + (m0 + srow[j]) * K + k0 + sgc[j], As + db);
      async16(B + (n0 + srow[j]) * K + k0 + sgc[j], Bs + db);
    }
    __syncthreads();

#pragma unroll
    for (int kc = 0; kc < 2; ++kc) {
      const int ch = (c0A ^ (kc * 4)) * 8;
      bf16x8 af[4], bfr[4];
#pragma unroll
      for (int t = 0; t < 4; ++t) {
        af[t]  = *(const bf16x8*)(As + (wm * 64 + t * 16 + l16) * 64 + ch);
        bfr[t] = *(const bf16x8*)(Bs + (wn * 64 + t * 16 + l16) * 64 + ch);
      }
#pragma unroll
      for (int mt = 0; mt < 4; ++mt)
#pragma unroll
        for (int nt = 0; nt < 4; ++nt)
          acc[mt][nt] = __builtin_amdgcn_mfma_f32_16x16x32_bf16(af[mt], bfr[nt],
                                                                acc[mt][nt], 0, 0, 0);
    }
  }

#pragma unroll
  for (int nt = 0; nt < 4; ++nt) {
    const long col = n0 + wn * 64 + nt * 16 + l16;
    float bv = 0.f;
    if (EPI == 1 || EPI == 2) bv = bias[col];
    const float scl = (EPI == 3 && col < 1024) ? CQK : 1.0f;
#pragma unroll
    for (int mt = 0; mt < 4; ++mt) {
#pragma unroll
      for (int r = 0; r < 4; ++r) {
        const long row = m0 + wm * 64 + mt * 16 + quad * 4 + r;
        const long idx = row * (long)N + col;
        float v = acc[mt][nt][r];
        if (EPI == 0) {
          ((unsigned short*)Cout)[idx] = f2bf(v);
        } else if (EPI == 1) {
          ((float*)Cout)[idx] = v + bv + res[idx];
        } else if (EPI == 2) {
          v += bv;
          ((unsigned short*)Cout)[idx] = f2bf(v > 0.f ? v : 0.f);
        } else {
          ((unsigned short*)Cout)[idx] = f2bf(v * scl);
        }
      }
    }
  }
}

// ---------------------------------------------------------------------------
// gemm_w2: 128(M)x256(N) tile, BK=64, 8-phase counted-vmcnt schedule.
// Re-parameterization of the R2 gemm256 (refcheck-passed) for the W2 GEMM
// (M=8192, N=1024, K=4096): grid = 64 x 4 = 256 blocks = exactly 1/CU, and
// K=4096 -> 32 deep-pipeline iterations (the regime where counted vmcnt pays;
// K=1024's 8 iterations did not).
// 512 thr = 8 waves (2M x 4N); per-wave acc[4][4]: row = mt*32+wm*16 (spans
// both A-halves), col = nt*64+wn*16 (nt pair 0/1 per B-half).
// LDS: A [2buf][2half][64x64]=32 KB + B [2buf][2half][128x64]=64 KB = 96 KB.
// Stage sizes: A-half = 1 load/thread, B-half = 2.  Per-phase event order
// fixed => vmcnt induction: outstanding at p4/p8 = 10, next tile = oldest 6
// -> s_waitcnt vmcnt(4).  Never drained in steady state.
// Quadrant order q00->q01->q11->q10, A-halves + B1 held in regs, B0 re-read.
// Epilogue: +bias +fp32 residual -> fp32 (gemm_bt EPI=1).
// ---------------------------------------------------------------------------
#define W2_LDA(AF, BUF, H)                                                      \
  do {                                                                          \
    const unsigned short* _p = As + ((BUF) * 2 + (H)) * 4096;                   \
    _Pragma("unroll") for (int _m = 0; _m < 2; ++_m) {                          \
      AF[_m][0] = *(const bf16x8*)(_p + (_m * 32 + rA) * 64 + chk0);            \
      AF[_m][1] = *(const bf16x8*)(_p + (_m * 32 + rA) * 64 + chk1);            \
    }                                                                           \
  } while (0)

#define W2_LDB(BF, BUF, H)                                                      \
  do {                                                                          \
    const unsigned short* _p = Bs + ((BUF) * 2 + (H)) * 8192;                   \
    _Pragma("unroll") for (int _n = 0; _n < 2; ++_n) {                          \
      BF[_n][0] = *(const bf16x8*)(_p + (_n * 64 + rB) * 64 + chk0);            \
      BF[_n][1] = *(const bf16x8*)(_p + (_n * 64 + rB) * 64 + chk1);            \
    }                                                                           \
  } while (0)

#define W2_MFMA(AH, BH, AF, BF)                                                 \
  do {                                                                          \
    _Pragma("unroll") for (int _m = 0; _m < 2; ++_m)                            \
    _Pragma("unroll") for (int _n = 0; _n < 2; ++_n) {                          \
      acc[(AH) * 2 + _m][(BH) * 2 + _n] =                                       \
          __builtin_amdgcn_mfma_f32_16x16x32_bf16(                              \
              AF[_m][0], BF[_n][0], acc[(AH) * 2 + _m][(BH) * 2 + _n], 0, 0, 0);\
      acc[(AH) * 2 + _m][(BH) * 2 + _n] =                                       \
          __builtin_amdgcn_mfma_f32_16x16x32_bf16(                              \
              AF[_m][1], BF[_n][1], acc[(AH) * 2 + _m][(BH) * 2 + _n], 0, 0, 0);\
    }                                                                           \
  } while (0)

#define PH_MID()                                                                \
  __builtin_amdgcn_s_barrier();                                                 \
  asm volatile("s_waitcnt lgkmcnt(0)" ::: "memory");                            \
  __builtin_amdgcn_sched_barrier(0);                                            \
  __builtin_amdgcn_s_setprio(1)

#define PH_END()                                                                \
  __builtin_amdgcn_s_setprio(0);                                                \
  __builtin_amdgcn_sched_barrier(0);                                            \
  __builtin_amdgcn_s_barrier();                                                 \
  __builtin_amdgcn_sched_barrier(0)

__launch_bounds__(512, 2)
__global__ void gemm_w2(const unsigned short* __restrict__ A,
                        const unsigned short* __restrict__ B,
                        float* __restrict__ Cout,
                        const float* __restrict__ bias,
                        const float* __restrict__ res,
                        int M, int N, int K) {
  extern __shared__ __align__(16) unsigned short lds[];
  unsigned short* As = lds;            // [2 buf][2 half][64*64]   32 KB
  unsigned short* Bs = lds + 16384;    // [2 buf][2 half][128*64]  64 KB

  const int tid  = threadIdx.x;
  const int lane = tid & 63;
  const int wv   = __builtin_amdgcn_readfirstlane(tid >> 6);  // 0..7
  const int quad = lane >> 4, l16 = lane & 15;
  const int wm = wv >> 2, wn = wv & 3;

  // 256 blocks: xcd m-banded (8 m-tiles x 4 n-tiles per XCD)
  const int id = blockIdx.x;
  const int xcd = id & 7, slot = id >> 3;        // slot 0..31
  const int by = xcd * 8 + (slot & 7);           // 0..63
  const int bx = slot >> 3;                      // 0..3
  const long m0 = (long)by * 128, n0 = (long)bx * 256;

  // staging: chunk s = wv*64+lane (0..511); row = s>>3, phys = s&7,
  // source logical chunk = phys ^ (row&7).  B uses a second set s+512.
  const int s0 = wv * 64 + lane;
  const int r0 = s0 >> 3;
  const int c0 = (s0 ^ r0) & 7;
  const int s1 = 512 + s0;
  const int r1 = s1 >> 3;
  const int c1 = (s1 ^ r1) & 7;
  const long rt0 = (long)r0 * K + c0 * 8;
  const long rt1 = (long)r1 * K + c1 * 8;
  const unsigned short* Ab = A + m0 * K;
  const unsigned short* Bb = B + n0 * K;

  // frag-read constants (phys chunk = logical(quad + kc*4) ^ (row&7))
  const int rA = wm * 16 + l16;          // 0..31 within 32-row frag band
  const int rB = wn * 16 + l16;          // 0..63 within 64-row frag band
  const int chk0 = (quad ^ (l16 & 7)) * 8;
  const int chk1 = chk0 ^ 32;

  f32x4 acc[4][4];
#pragma unroll
  for (int a_ = 0; a_ < 4; ++a_)
#pragma unroll
    for (int b_ = 0; b_ < 4; ++b_) acc[a_][b_] = (f32x4){0.f, 0.f, 0.f, 0.f};

  auto stgA = [&](int b, int h, long kk) {   // 1 load/thread (64 rows)
    const unsigned short* s = Ab + (long)h * 64 * K + kk;
    async16(s + rt0, As + (b * 2 + h) * 4096 + wv * 512);
  };
  auto stgB = [&](int b, int h, long kk) {   // 2 loads/thread (128 rows)
    const unsigned short* s = Bb + (long)h * 128 * K + kk;
    unsigned short* d = Bs + (b * 2 + h) * 8192 + wv * 512;
    async16(s + rt0, d);
    async16(s + rt1, d + 4096);
  };

  // prologue: tile0 fully (6 loads, buf0), then tile1's A0,B1,A1 (4, buf1).
  // tile1.B0 staged in iter0's p1.  outstanding 10 -> vmcnt(4) == tile0 landed.
  stgA(0, 0, 0); stgB(0, 1, 0); stgA(0, 1, 0); stgB(0, 0, 0);
  stgA(1, 0, 64); stgB(1, 1, 64); stgA(1, 1, 64);
  asm volatile("s_waitcnt vmcnt(4)" ::: "memory");
  __builtin_amdgcn_s_barrier();
  __builtin_amdgcn_sched_barrier(0);

  const int NI = K >> 7;   // 32 iterations (2 K-tiles per iter)
  for (int it = 0; it < NI; ++it) {
    const long kt  = (long)it * 128;
    const long ku  = kt + 64;
    const long kt2 = kt + 128;
    const long kt3 = kt + 192;
    const bool more = (it + 1 < NI);

    // ================= tile t (buf0) =================
    {
      bf16x8 a0[2][2], a1[2][2], b0[2][2], b1[2][2];
      // p1: q00 = A0 x B0
      W2_LDA(a0, 0, 0); W2_LDB(b0, 0, 0);
      stgB(1, 0, ku);                        // u.B0 (slot died at prev p8)
      PH_MID();
      W2_MFMA(0, 0, a0, b0);
      PH_END();
      // p2: q01 = A0 x B1 (a0 held)
      W2_LDB(b1, 0, 1);
      if (more) stgA(0, 0, kt2);             // t2.A0 (t.A0 died after p1)
      PH_MID();
      W2_MFMA(0, 1, a0, b1);
      PH_END();
      // p3: q11 = A1 x B1 (b1 held)
      W2_LDA(a1, 0, 1);
      if (more) stgB(0, 1, kt2);             // t2.B1 (t.B1 died after p2)
      PH_MID();
      W2_MFMA(1, 1, a1, b1);
      PH_END();
      // p4: q10 = A1 x B0 (re-read B0; a1 held)
      W2_LDB(b0, 0, 0);
      if (more) stgA(0, 1, kt2);             // t2.A1 (t.A1 died after p3)
      PH_MID();
      W2_MFMA(1, 0, a1, b0);
      __builtin_amdgcn_s_setprio(0);
      __builtin_amdgcn_sched_barrier(0);
      if (more) { asm volatile("s_waitcnt vmcnt(4)" ::: "memory"); }  // u landed
      else      { asm volatile("s_waitcnt vmcnt(0)" ::: "memory"); }
      __builtin_amdgcn_s_barrier();
      __builtin_amdgcn_sched_barrier(0);
    }
    // ================= tile u (buf1) =================
    {
      bf16x8 a0[2][2], a1[2][2], b0[2][2], b1[2][2];
      // p5: q00
      W2_LDA(a0, 1, 0); W2_LDB(b0, 1, 0);
      if (more) stgB(0, 0, kt2);             // t2.B0 (t.B0 died after p4)
      PH_MID();
      W2_MFMA(0, 0, a0, b0);
      PH_END();
      // p6: q01
      W2_LDB(b1, 1, 1);
      if (more) stgA(1, 0, kt3);             // t3.A0 (u.A0 died after p5)
      PH_MID();
      W2_MFMA(0, 1, a0, b1);
      PH_END();
      // p7: q11
      W2_LDA(a1, 1, 1);
      if (more) stgB(1, 1, kt3);             // t3.B1 (u.B1 died after p6)
      PH_MID();
      W2_MFMA(1, 1, a1, b1);
      PH_END();
      // p8: q10
      W2_LDB(b0, 1, 0);
      if (more) stgA(1, 1, kt3);             // t3.A1 (u.A1 died after p7)
      PH_MID();
      W2_MFMA(1, 0, a1, b0);
      __builtin_amdgcn_s_setprio(0);
      __builtin_amdgcn_sched_barrier(0);
      if (more) { asm volatile("s_waitcnt vmcnt(4)" ::: "memory"); }  // t2 landed
      __builtin_amdgcn_s_barrier();
      __builtin_amdgcn_sched_barrier(0);
    }
  }

  // epilogue: +bias +fp32 residual -> fp32
#pragma unroll
  for (int nt = 0; nt < 4; ++nt) {
    const long col = n0 + nt * 64 + wn * 16 + l16;
    const float bv = bias[col];
#pragma unroll
    for (int mt = 0; mt < 4; ++mt) {
#pragma unroll
      for (int r = 0; r < 4; ++r) {
        const long row = m0 + mt * 32 + wm * 16 + quad * 4 + r;
        const long idx = row * (long)N + col;
        Cout[idx] = acc[mt][nt][r] + bv + res[idx];
      }
    }
  }
}

// ---------------------------------------------------------------------------
// vprep: V (cols 2048.. of qkv) -> per-(b,h,kv-tile) async16-ready tiles.
// ---------------------------------------------------------------------------
__global__ void vprep(const unsigned short* __restrict__ qkv,
                      unsigned short* __restrict__ vt) {
  __shared__ unsigned short T[64 * 68];
  const int tid = threadIdx.x;           // 256
  const int t = blockIdx.x;              // kv tile 0..31
  const int bh = blockIdx.y;             // 0..63
  const int b = bh >> 4, h = bh & 15;
  const long base = ((long)b * 2048 + t * 64) * 3072 + 2048 + h * 64;
#pragma unroll
  for (int i = 0; i < 4; ++i) {
    int c = i * 256 + tid;
    int r = c >> 4, d4 = (c & 15) * 4;
    *(ushort4*)(T + r * 68 + d4) = *(const ushort4*)(qkv + base + (long)r * 3072 + d4);
  }
  __syncthreads();
  unsigned short* out = vt + ((long)bh * 32 + t) * 4096;
#pragma unroll
  for (int i = 0; i < 4; ++i) {
    int u = i * 256 + tid;               // ushort4 index 0..1023
    int c = u >> 1, half = u & 1;
    int d = c >> 3;
    int k = ((c & 7) - d) & 7;
    int kvp4 = k * 8 + half * 4;
    int sk = (kvp4 & 32) | ((kvp4 & 4) << 2) | ((kvp4 & 16) >> 1) | ((kvp4 & 8) >> 1);
    ushort4 o;
    o.x = T[(sk + 0) * 68 + d];
    o.y = T[(sk + 1) * 68 + d];
    o.z = T[(sk + 2) * 68 + d];
    o.w = T[(sk + 3) * 68 + d];
    *(ushort4*)(out + u * 4) = o;
  }
}

// ---------------------------------------------------------------------------
// Flash attention fwd, S^T formulation, fixed-base softmax.  (v4, unchanged:
// Q direct-to-reg, KVBLK=64, 32 KB dbuf LDS, counted vmcnt(4), setprio.)
// ---------------------------------------------------------------------------
__launch_bounds__(256, 4)
__global__ void attn_fwd(const unsigned short* __restrict__ qkv,
                         const unsigned short* __restrict__ vt,
                         unsigned short* __restrict__ outp) {
  // 32 KB: [K0 | K1 | V0 | V1], 8 KB (4096 ushorts) each
  __shared__ __align__(16) unsigned short lds[16384];

  const int tid = threadIdx.x;
  const int lane = tid & 63;
  const int wv = __builtin_amdgcn_readfirstlane(tid >> 6);  // 0..3
  const int quad = lane >> 4, l16 = lane & 15;

  // XCD-packed remap: xcd = id&7 owns heads [xcd*8, xcd*8+8)
  const int id = blockIdx.y * 16 + blockIdx.x;   // grid (16, 64)
  const int xcd = id & 7, slot = id >> 3;        // slot 0..127
  const int bh = xcd * 8 + (slot >> 4);
  const int qt = slot & 15;
  const int b = bh >> 4, h = bh & 15;
  const long rowbase = (long)b * 2048;
  const int hoff = h * 64;

  const int rot0 = (quad + l16) & 7;
  const int rot1 = rot0 ^ 4;

  // ---- Q direct to registers (4 x 16B loads, one-time) ----
  bf16x8 bq[2][2];
#pragma unroll
  for (int s = 0; s < 2; ++s) {
    const long qrow = rowbase + qt * 128 + wv * 32 + s * 16 + l16;
    const unsigned short* qp = qkv + qrow * 3072 + hoff;
    bq[s][0] = *(const bf16x8*)(qp + quad * 8);
    bq[s][1] = *(const bf16x8*)(qp + (quad ^ 4) * 8);
  }
  __builtin_amdgcn_sched_barrier(0);   // keep bq loads issued before staging

  // staging constants: 512 chunks per 64-kv tile, 2 sets of 256
  const int c0 = wv * 64 + lane;          // chunk 0..255
  const int r0 = c0 >> 3;                 // row 0..31
  const int ks = ((c0 & 7) - r0) & 7;
  const unsigned short* kptr = qkv + (rowbase + r0) * 3072 + 1024 + hoff + ks * 8;
  const unsigned short* vptr = vt + (long)bh * 131072 + (long)c0 * 8;

  auto stage = [&](int t) {   // 64-kv tile t -> buffers t&1 (4 loads/wave)
    unsigned short* kdst = lds + (t & 1) * 4096 + wv * 512;
    unsigned short* vdst = lds + 8192 + (t & 1) * 4096 + wv * 512;
    const unsigned short* kp = kptr + (long)t * 64 * 3072;
    const unsigned short* vp = vptr + (long)t * 4096;
#pragma unroll
    for (int j = 0; j < 2; ++j) {
      async16(kp + (long)j * 32 * 3072, kdst + j * 2048);
      async16(vp + j * 2048, vdst + j * 2048);
    }
  };

  bf16x8 ones;
#pragma unroll
  for (int i = 0; i < 8; ++i) ones[i] = (short)0x3F80;

  f32x4 oacc[2][4], lacc[2];
#pragma unroll
  for (int s = 0; s < 2; ++s) {
    lacc[s] = (f32x4){0.f, 0.f, 0.f, 0.f};
#pragma unroll
    for (int i = 0; i < 4; ++i) oacc[s][i] = (f32x4){0.f, 0.f, 0.f, 0.f};
  }

  // prologue: bq(4) + tile0(4) + tile1(4) outstanding; vmcnt(4) -> bq+tile0 done
  stage(0); stage(1);
  asm volatile("s_waitcnt vmcnt(4)" ::: "memory");
  __builtin_amdgcn_s_barrier();
  __builtin_amdgcn_sched_barrier(0);

  for (int kt = 0; kt < 32; ++kt) {
    const unsigned short* Kb = lds + (kt & 1) * 4096;
    const unsigned short* Vb = lds + 8192 + (kt & 1) * 4096;

    // St = K.Q^T for both strips; ak frags shared
    f32x4 sacc[2][4];
    __builtin_amdgcn_s_setprio(1);
#pragma unroll
    for (int t = 0; t < 4; ++t) {
      const int ar = t * 16 + l16;
      bf16x8 ak0 = *(const bf16x8*)(Kb + ar * 64 + rot0 * 8);
      bf16x8 ak1 = *(const bf16x8*)(Kb + ar * 64 + rot1 * 8);
#pragma unroll
      for (int s = 0; s < 2; ++s) {
        f32x4 z = (f32x4){0.f, 0.f, 0.f, 0.f};
        z = __builtin_amdgcn_mfma_f32_16x16x32_bf16(ak0, bq[s][0], z, 0, 0, 0);
        sacc[s][t] = __builtin_amdgcn_mfma_f32_16x16x32_bf16(ak1, bq[s][1], z, 0, 0, 0);
      }
    }
    __builtin_amdgcn_s_setprio(0);

    // fixed-base softmax: p = exp2(s); pack to A-frags; l via ones-MFMA
    union APU { unsigned u[4]; bf16x8 v; } ap[2][2];
#pragma unroll
    for (int s = 0; s < 2; ++s)
#pragma unroll
      for (int hf = 0; hf < 2; ++hf) {
#pragma unroll
        for (int t = 0; t < 2; ++t) {
          const f32x4 sv = sacc[s][hf * 2 + t];
          const float p0 = __builtin_amdgcn_exp2f(sv[0]);
          const float p1 = __builtin_amdgcn_exp2f(sv[1]);
          const float p2 = __builtin_amdgcn_exp2f(sv[2]);
          const float p3 = __builtin_amdgcn_exp2f(sv[3]);
          ap[s][hf].u[t * 2 + 0] = pk2(p0, p1);
          ap[s][hf].u[t * 2 + 1] = pk2(p2, p3);
        }
        lacc[s] = __builtin_amdgcn_mfma_f32_16x16x32_bf16(ap[s][hf].v, ones,
                                                          lacc[s], 0, 0, 0);
      }

    // O += P.V : bv frags shared across both strips
    __builtin_amdgcn_s_setprio(1);
#pragma unroll
    for (int hf = 0; hf < 2; ++hf) {
      const int vbase = (hf ? rot1 : rot0) * 8;
#pragma unroll
      for (int dt = 0; dt < 4; ++dt) {
        bf16x8 bv = *(const bf16x8*)(Vb + vbase + (dt * 16 + l16) * 64);
#pragma unroll
        for (int s = 0; s < 2; ++s)
          oacc[s][dt] = __builtin_amdgcn_mfma_f32_16x16x32_bf16(ap[s][hf].v, bv,
                                                                oacc[s][dt], 0, 0, 0);
      }
    }
    __builtin_amdgcn_s_setprio(0);

    if (kt == 31) break;
    __builtin_amdgcn_s_barrier();          // all waves done reading buf(kt&1)
    __builtin_amdgcn_sched_barrier(0);
    if (kt + 2 < 32) {
      stage(kt + 2);                       // overwrite just-read buffer
      asm volatile("s_waitcnt vmcnt(4)" ::: "memory");   // tile kt+1 landed
    } else {
      asm volatile("s_waitcnt vmcnt(0)" ::: "memory");   // last tile: drain once
    }
    __builtin_amdgcn_s_barrier();          // tile kt+1 visible to all waves
    __builtin_amdgcn_sched_barrier(0);
  }

  // epilogue: q-row = wv*32 + s*16 + quad*4 + r; lacc already in that layout
#pragma unroll
  for (int s = 0; s < 2; ++s) {
    float linv[4];
#pragma unroll
    for (int r = 0; r < 4; ++r) linv[r] = 1.f / lacc[s][r];
#pragma unroll
    for (int dt = 0; dt < 4; ++dt)
#pragma unroll
      for (int r = 0; r < 4; ++r) {
        const long row = rowbase + qt * 128 + wv * 32 + s * 16 + quad * 4 + r;
        outp[row * 1024 + hoff + dt * 16 + l16] = f2bf(oacc[s][dt][r] * linv[r]);
      }
  }
}

// ---------------------------------------------------------------------------
// launch
// ---------------------------------------------------------------------------
extern "C" void kernel_launch(void* const* d_in, const int* in_sizes, int n_in,
                              void* d_out, int out_size, void* d_ws, size_t ws_size,
                              hipStream_t stream) {
  (void)in_sizes; (void)n_in; (void)out_size; (void)ws_size;
  const float* x   = (const float*)d_in[0];
  const float* Wq  = (const float*)d_in[1];
  const float* Wk  = (const float*)d_in[2];
  const float* Wv  = (const float*)d_in[3];
  const float* Wo  = (const float*)d_in[4];
  const float* bo  = (const float*)d_in[5];
  const float* g1  = (const float*)d_in[6];
  const float* be1 = (const float*)d_in[7];
  const float* g2  = (const float*)d_in[8];
  const float* be2 = (const float*)d_in[9];
  const float* W1  = (const float*)d_in[10];
  const float* bf1 = (const float*)d_in[11];
  const float* W2  = (const float*)d_in[12];
  const float* bf2 = (const float*)d_in[13];

  static bool s_attr = false;
  if (!s_attr) {
    hipFuncSetAttribute(reinterpret_cast<const void*>(&gemm_w2),
                        hipFuncAttributeMaxDynamicSharedMemorySize, 98304);
    s_attr = true;
  }

  char* ws = (char*)d_ws;
  unsigned short* wqkv  = (unsigned short*)(ws);              // [3072,1024] bf16   6 MiB
  unsigned short* wo    = (unsigned short*)(ws + 6291456);    // [1024,1024]        2 MiB
  unsigned short* w1    = (unsigned short*)(ws + 8388608);    // [4096,1024]        8 MiB
  unsigned short* w2    = (unsigned short*)(ws + 16777216);   // [1024,4096]        8 MiB
  unsigned short* xn    = (unsigned short*)(ws + 25165824);   // [8192,1024]       16 MiB
  unsigned short* big   = (unsigned short*)(ws + 41943040);   // qkv/h             64 MiB
  unsigned short* attnb = (unsigned short*)(ws + 109051904);  // [8192,1024]       16 MiB
  float*          x1    = (float*)(ws + 125829120);           // [8192,1024] f32   32 MiB
  // vtg aliases xn: LN1's xn dead after QKV GEMM; attn consumes before LN2.
  unsigned short* vtg   = xn;                                 // [64][32][4096]    16 MiB

  cvt_all<<<12288, 256, 0, stream>>>(Wq, Wk, Wv, Wo, W1, W2, wqkv);

  ln_fwd<<<8192, 256, 0, stream>>>(x, g1, be1, xn);
  gemm_bt<3><<<dim3(24, 64), 256, 0, stream>>>(xn, wqkv, big, nullptr, nullptr,
                                               8192, 3072, 1024);
  vprep<<<dim3(32, 64), 256, 0, stream>>>(big, vtg);
  attn_fwd<<<dim3(16, 64), 256, 0, stream>>>(big, vtg, attnb);
  gemm_bt<1><<<dim3(8, 64), 256, 0, stream>>>(attnb, wo, x1, bo, x,
                                              8192, 1024, 1024);
  ln_fwd<<<8192, 256, 0, stream>>>(x1, g2, be2, xn);
  gemm_bt<2><<<dim3(32, 64), 256, 0, stream>>>(xn, w1, big, bf1, nullptr,
                                               8192, 4096, 1024);
  gemm_w2<<<dim3(256), 512, 98304, stream>>>(big, w2, (float*)d_out, bf2, x1,
                                             8192, 1024, 4096);
}

// Round 6
// 449.662 us; speedup vs baseline: 1.0915x; 1.0558x over previous
//
#include <hip/hip_runtime.h>
#include <hip/hip_bf16.h>
#include <cstdint>

// ---------------------------------------------------------------------------
// TransBlock: pre-LN transformer encoder block, bf16 MFMA compute, fp32 I/O.
// B=4 S=2048 E=1024 H=16 Dh=64 Dff=4096.  M = B*S = 8192 rows.
// ---------------------------------------------------------------------------

typedef __attribute__((ext_vector_type(8))) short bf16x8;   // 4 VGPRs, MFMA A/B frag
typedef __attribute__((ext_vector_type(4))) float f32x4;    // MFMA C/D frag

#define LDSAS __attribute__((address_space(3)))
#define GLBAS __attribute__((address_space(1)))

#define CQK 0.18033688011112044f   // (1/8) * log2(e), folded into Q at QKV epilogue

union APU { unsigned u[4]; bf16x8 v; };

__device__ __forceinline__ unsigned short f2bf(float f) {
  union { float f; unsigned u; } c; c.f = f;
  unsigned u = c.u + 0x7fffu + ((c.u >> 16) & 1u);   // RNE
  return (unsigned short)(u >> 16);
}

__device__ __forceinline__ unsigned pk2(float a, float b) {  // v_cvt_pk path
  __hip_bfloat162 h = __float22bfloat162_rn(make_float2(a, b));
  union { __hip_bfloat162 h; unsigned u; } c; c.h = h; return c.u;
}

// async global->LDS, 16B/lane, dest = wave-uniform base + lane*16
__device__ __forceinline__ void async16(const unsigned short* g, unsigned short* l) {
  __builtin_amdgcn_global_load_lds((const GLBAS unsigned int*)g,
                                   (LDSAS unsigned int*)l, 16, 0, 0);
}

// ---------------------------------------------------------------------------
// cvt_all: all six fp32 weight arrays -> bf16 workspace in ONE launch.
// ---------------------------------------------------------------------------
__global__ void cvt_all(const float* __restrict__ q, const float* __restrict__ k,
                        const float* __restrict__ v, const float* __restrict__ o,
                        const float* __restrict__ w1, const float* __restrict__ w2,
                        unsigned short* __restrict__ wsb) {
  const long i = (long)blockIdx.x * 256 + threadIdx.x;   // float4 index
  const float* src; unsigned short* dst; long off;
  if (i < 1048576) {
    const long seg = i >> 18, o4 = i & 262143;
    src = (seg == 0) ? q : (seg == 1) ? k : (seg == 2) ? v : o;
    dst = wsb + ((seg == 3) ? 3145728L : seg * 1048576L);
    off = o4;
  } else if (i < 2097152) {
    src = w1; dst = wsb + 4194304; off = i - 1048576;
  } else {
    src = w2; dst = wsb + 8388608; off = i - 2097152;
  }
  const float4 vv = ((const float4*)src)[off];
  ushort4 r;
  r.x = f2bf(vv.x); r.y = f2bf(vv.y); r.z = f2bf(vv.z); r.w = f2bf(vv.w);
  ((ushort4*)dst)[off] = r;
}

// ---------------------------------------------------------------------------
// LayerNorm: one block per row of 1024, fp32 in -> bf16 out
// ---------------------------------------------------------------------------
__global__ void ln_fwd(const float* __restrict__ x, const float* __restrict__ g,
                       const float* __restrict__ bb, unsigned short* __restrict__ outp) {
  const int row = blockIdx.x, tid = threadIdx.x;
  const float4 v = ((const float4*)(x + (long)row * 1024))[tid];
  float s  = v.x + v.y + v.z + v.w;
  float sq = v.x * v.x + v.y * v.y + v.z * v.z + v.w * v.w;
#pragma unroll
  for (int off = 1; off < 64; off <<= 1) {
    s  += __shfl_xor(s, off);
    sq += __shfl_xor(sq, off);
  }
  __shared__ float red[8];
  const int wv = tid >> 6, lane = tid & 63;
  if (lane == 0) { red[wv] = s; red[4 + wv] = sq; }
  __syncthreads();
  s  = red[0] + red[1] + red[2] + red[3];
  sq = red[4] + red[5] + red[6] + red[7];
  const float mu  = s * (1.f / 1024.f);
  const float var = sq * (1.f / 1024.f) - mu * mu;
  const float rstd = rsqrtf(var + 1e-5f);
  const float4 gv = ((const float4*)g)[tid];
  const float4 bv = ((const float4*)bb)[tid];
  ushort4 o;
  o.x = f2bf((v.x - mu) * rstd * gv.x + bv.x);
  o.y = f2bf((v.y - mu) * rstd * gv.y + bv.y);
  o.z = f2bf((v.z - mu) * rstd * gv.z + bv.z);
  o.w = f2bf((v.w - mu) * rstd * gv.w + bv.w);
  ((ushort4*)(outp + (long)row * 1024))[tid] = o;
}

// ---------------------------------------------------------------------------
// B^T GEMM: C[M,N] = A[M,K](bf16) . B[N,K](bf16)^T
// 128x128 tile, BK=64, 256 thr = 4 waves in 2x2, per wave 4x4x2 16x16x32 MFMA.
// Used for K=1024 GEMMs (QKV, Wo, W1).
// EPI: 0 = store bf16; 1 = +bias +fp32 residual -> fp32; 2 = +bias, relu -> bf16
//      3 = QKV epilogue: cols<1024 *CQK -> big; cols 1024..2047 -> big;
//          cols>=2048 (V) scattered DIRECTLY into vt tiles (vprep fused away).
//          vprep inverse perm: kvp4=(sk&32)|((sk&16)>>2)|((sk&8)<<1)|((sk&4)<<1);
//          k=kvp4>>3, half=(kvp4>>2)&1; c=d*8+((k+d)&7); u=c*2+half; j=r.
// ---------------------------------------------------------------------------
template <int EPI>
__launch_bounds__(256, 3)
__global__ void gemm_bt(const unsigned short* __restrict__ A,
                        const unsigned short* __restrict__ B,
                        void* __restrict__ Cout,
                        const float* __restrict__ bias,
                        const float* __restrict__ res,
                        unsigned short* __restrict__ vt4,
                        int M, int N, int K) {
  __shared__ __align__(16) unsigned short As[128 * 64];   // 16 KB each
  __shared__ __align__(16) unsigned short Bs[128 * 64];
  const int tid  = threadIdx.x;
  const int lane = tid & 63;
  const int wvu  = __builtin_amdgcn_readfirstlane(tid >> 6);  // wave id, SGPR
  const int quad = lane >> 4, l16 = lane & 15;
  const int wm = wvu >> 1, wn = wvu & 1;

  const int gx = gridDim.x;
  const int id = blockIdx.y * gx + blockIdx.x;
  const int xcd = id & 7, slot = id >> 3;
  const int by = xcd * 8 + (slot & 7);
  const int bx = slot >> 3;
  const long m0 = (long)by * 128, n0 = (long)bx * 128;

  f32x4 acc[4][4];
#pragma unroll
  for (int i = 0; i < 4; i++)
#pragma unroll
    for (int j = 0; j < 4; j++) acc[i][j] = (f32x4){0.f, 0.f, 0.f, 0.f};

  const int rxA = l16 & 7;
  const int c0A = quad ^ rxA;              // kc=0 phys chunk for frag reads
  int srow[4], sgc[4];
#pragma unroll
  for (int j = 0; j < 4; ++j) {
    const int s = wvu * 256 + j * 64 + lane;
    srow[j] = s >> 3;
    sgc[j] = ((s & 7) ^ (srow[j] & 7)) * 8;
  }

  for (int k0 = 0; k0 < K; k0 += 64) {
    __syncthreads();
#pragma unroll
    for (int j = 0; j < 4; ++j) {
      const int db = (wvu * 256 + j * 64) * 8;   // wave-uniform LDS base (elems)
      async16(A + (m0 + srow[j]) * K + k0 + sgc[j], As + db);
      async16(B + (n0 + srow[j]) * K + k0 + sgc[j], Bs + db);
    }
    __syncthreads();

#pragma unroll
    for (int kc = 0; kc < 2; ++kc) {
      const int ch = (c0A ^ (kc * 4)) * 8;
      bf16x8 af[4], bfr[4];
#pragma unroll
      for (int t = 0; t < 4; ++t) {
        af[t]  = *(const bf16x8*)(As + (wm * 64 + t * 16 + l16) * 64 + ch);
        bfr[t] = *(const bf16x8*)(Bs + (wn * 64 + t * 16 + l16) * 64 + ch);
      }
#pragma unroll
      for (int mt = 0; mt < 4; ++mt)
#pragma unroll
        for (int nt = 0; nt < 4; ++nt)
          acc[mt][nt] = __builtin_amdgcn_mfma_f32_16x16x32_bf16(af[mt], bfr[nt],
                                                                acc[mt][nt], 0, 0, 0);
    }
  }

  if (EPI == 3) {
#pragma unroll
    for (int nt = 0; nt < 4; ++nt) {
      const long col = n0 + wn * 64 + nt * 16 + l16;
      if (col < 2048) {                      // block-uniform branch (128 | 2048)
        const float scl = (col < 1024) ? CQK : 1.0f;
#pragma unroll
        for (int mt = 0; mt < 4; ++mt)
#pragma unroll
          for (int r = 0; r < 4; ++r) {
            const long row = m0 + wm * 64 + mt * 16 + quad * 4 + r;
            ((unsigned short*)Cout)[row * (long)N + col] = f2bf(acc[mt][nt][r] * scl);
          }
      } else {                               // V -> vt tiles (vprep fused)
        const int hd = (int)(col - 2048);
        const int h = hd >> 6, d = hd & 63;
#pragma unroll
        for (int mt = 0; mt < 4; ++mt) {
          const long row = m0 + wm * 64 + mt * 16 + quad * 4;   // mult of 4
          const int b_ = (int)(row >> 11);
          const int kv = (int)(row & 2047);
          const int t_ = kv >> 6;
          const int sk = kv & 63;            // multiple of 4; j = r
          const int kvp4 = (sk & 32) | ((sk & 16) >> 2) | ((sk & 8) << 1) | ((sk & 4) << 1);
          const int kk = kvp4 >> 3, half = (kvp4 >> 2) & 1;
          const int cc = d * 8 + ((kk + d) & 7);
          const int u = cc * 2 + half;
          ushort4 o;
          o.x = f2bf(acc[mt][nt][0]);
          o.y = f2bf(acc[mt][nt][1]);
          o.z = f2bf(acc[mt][nt][2]);
          o.w = f2bf(acc[mt][nt][3]);
          *(ushort4*)(vt4 + ((long)((b_ * 16 + h) * 32 + t_)) * 4096 + u * 4) = o;
        }
      }
    }
  } else {
#pragma unroll
    for (int nt = 0; nt < 4; ++nt) {
      const long col = n0 + wn * 64 + nt * 16 + l16;
      float bv = 0.f;
      if (EPI == 1 || EPI == 2) bv = bias[col];
#pragma unroll
      for (int mt = 0; mt < 4; ++mt) {
#pragma unroll
        for (int r = 0; r < 4; ++r) {
          const long row = m0 + wm * 64 + mt * 16 + quad * 4 + r;
          const long idx = row * (long)N + col;
          float v = acc[mt][nt][r];
          if (EPI == 0) {
            ((unsigned short*)Cout)[idx] = f2bf(v);
          } else if (EPI == 1) {
            ((float*)Cout)[idx] = v + bv + res[idx];
          } else {
            v += bv;
            ((unsigned short*)Cout)[idx] = f2bf(v > 0.f ? v : 0.f);
          }
        }
      }
    }
  }
}

// ---------------------------------------------------------------------------
// gemm_w2: 128(M)x256(N) tile, BK=64, 8-phase counted-vmcnt schedule.
// (unchanged from R4; used only for W2: M=8192 N=1024 K=4096, 256 blocks.)
// ---------------------------------------------------------------------------
#define W2_LDA(AF, BUF, H)                                                      \
  do {                                                                          \
    const unsigned short* _p = As + ((BUF) * 2 + (H)) * 4096;                   \
    _Pragma("unroll") for (int _m = 0; _m < 2; ++_m) {                          \
      AF[_m][0] = *(const bf16x8*)(_p + (_m * 32 + rA) * 64 + chk0);            \
      AF[_m][1] = *(const bf16x8*)(_p + (_m * 32 + rA) * 64 + chk1);            \
    }                                                                           \
  } while (0)

#define W2_LDB(BF, BUF, H)                                                      \
  do {                                                                          \
    const unsigned short* _p = Bs + ((BUF) * 2 + (H)) * 8192;                   \
    _Pragma("unroll") for (int _n = 0; _n < 2; ++_n) {                          \
      BF[_n][0] = *(const bf16x8*)(_p + (_n * 64 + rB) * 64 + chk0);            \
      BF[_n][1] = *(const bf16x8*)(_p + (_n * 64 + rB) * 64 + chk1);            \
    }                                                                           \
  } while (0)

#define W2_MFMA(AH, BH, AF, BF)                                                 \
  do {                                                                          \
    _Pragma("unroll") for (int _m = 0; _m < 2; ++_m)                            \
    _Pragma("unroll") for (int _n = 0; _n < 2; ++_n) {                          \
      acc[(AH) * 2 + _m][(BH) * 2 + _n] =                                       \
          __builtin_amdgcn_mfma_f32_16x16x32_bf16(                              \
              AF[_m][0], BF[_n][0], acc[(AH) * 2 + _m][(BH) * 2 + _n], 0, 0, 0);\
      acc[(AH) * 2 + _m][(BH) * 2 + _n] =                                       \
          __builtin_amdgcn_mfma_f32_16x16x32_bf16(                              \
              AF[_m][1], BF[_n][1], acc[(AH) * 2 + _m][(BH) * 2 + _n], 0, 0, 0);\
    }                                                                           \
  } while (0)

#define PH_MID()                                                                \
  __builtin_amdgcn_s_barrier();                                                 \
  asm volatile("s_waitcnt lgkmcnt(0)" ::: "memory");                            \
  __builtin_amdgcn_sched_barrier(0);                                            \
  __builtin_amdgcn_s_setprio(1)

#define PH_END()                                                                \
  __builtin_amdgcn_s_setprio(0);                                                \
  __builtin_amdgcn_sched_barrier(0);                                            \
  __builtin_amdgcn_s_barrier();                                                 \
  __builtin_amdgcn_sched_barrier(0)

__launch_bounds__(512, 2)
__global__ void gemm_w2(const unsigned short* __restrict__ A,
                        const unsigned short* __restrict__ B,
                        float* __restrict__ Cout,
                        const float* __restrict__ bias,
                        const float* __restrict__ res,
                        int M, int N, int K) {
  extern __shared__ __align__(16) unsigned short lds[];
  unsigned short* As = lds;            // [2 buf][2 half][64*64]   32 KB
  unsigned short* Bs = lds + 16384;    // [2 buf][2 half][128*64]  64 KB

  const int tid  = threadIdx.x;
  const int lane = tid & 63;
  const int wv   = __builtin_amdgcn_readfirstlane(tid >> 6);  // 0..7
  const int quad = lane >> 4, l16 = lane & 15;
  const int wm = wv >> 2, wn = wv & 3;

  const int id = blockIdx.x;
  const int xcd = id & 7, slot = id >> 3;        // slot 0..31
  const int by = xcd * 8 + (slot & 7);           // 0..63
  const int bx = slot >> 3;                      // 0..3
  const long m0 = (long)by * 128, n0 = (long)bx * 256;

  const int s0 = wv * 64 + lane;
  const int r0 = s0 >> 3;
  const int c0 = (s0 ^ r0) & 7;
  const int s1 = 512 + s0;
  const int r1 = s1 >> 3;
  const int c1 = (s1 ^ r1) & 7;
  const long rt0 = (long)r0 * K + c0 * 8;
  const long rt1 = (long)r1 * K + c1 * 8;
  const unsigned short* Ab = A + m0 * K;
  const unsigned short* Bb = B + n0 * K;

  const int rA = wm * 16 + l16;
  const int rB = wn * 16 + l16;
  const int chk0 = (quad ^ (l16 & 7)) * 8;
  const int chk1 = chk0 ^ 32;

  f32x4 acc[4][4];
#pragma unroll
  for (int a_ = 0; a_ < 4; ++a_)
#pragma unroll
    for (int b_ = 0; b_ < 4; ++b_) acc[a_][b_] = (f32x4){0.f, 0.f, 0.f, 0.f};

  auto stgA = [&](int b, int h, long kk) {
    const unsigned short* s = Ab + (long)h * 64 * K + kk;
    async16(s + rt0, As + (b * 2 + h) * 4096 + wv * 512);
  };
  auto stgB = [&](int b, int h, long kk) {
    const unsigned short* s = Bb + (long)h * 128 * K + kk;
    unsigned short* d = Bs + (b * 2 + h) * 8192 + wv * 512;
    async16(s + rt0, d);
    async16(s + rt1, d + 4096);
  };

  stgA(0, 0, 0); stgB(0, 1, 0); stgA(0, 1, 0); stgB(0, 0, 0);
  stgA(1, 0, 64); stgB(1, 1, 64); stgA(1, 1, 64);
  asm volatile("s_waitcnt vmcnt(4)" ::: "memory");
  __builtin_amdgcn_s_barrier();
  __builtin_amdgcn_sched_barrier(0);

  const int NI = K >> 7;
  for (int it = 0; it < NI; ++it) {
    const long kt  = (long)it * 128;
    const long ku  = kt + 64;
    const long kt2 = kt + 128;
    const long kt3 = kt + 192;
    const bool more = (it + 1 < NI);

    {
      bf16x8 a0[2][2], a1[2][2], b0[2][2], b1[2][2];
      W2_LDA(a0, 0, 0); W2_LDB(b0, 0, 0);
      stgB(1, 0, ku);
      PH_MID();
      W2_MFMA(0, 0, a0, b0);
      PH_END();
      W2_LDB(b1, 0, 1);
      if (more) stgA(0, 0, kt2);
      PH_MID();
      W2_MFMA(0, 1, a0, b1);
      PH_END();
      W2_LDA(a1, 0, 1);
      if (more) stgB(0, 1, kt2);
      PH_MID();
      W2_MFMA(1, 1, a1, b1);
      PH_END();
      W2_LDB(b0, 0, 0);
      if (more) stgA(0, 1, kt2);
      PH_MID();
      W2_MFMA(1, 0, a1, b0);
      __builtin_amdgcn_s_setprio(0);
      __builtin_amdgcn_sched_barrier(0);
      if (more) { asm volatile("s_waitcnt vmcnt(4)" ::: "memory"); }
      else      { asm volatile("s_waitcnt vmcnt(0)" ::: "memory"); }
      __builtin_amdgcn_s_barrier();
      __builtin_amdgcn_sched_barrier(0);
    }
    {
      bf16x8 a0[2][2], a1[2][2], b0[2][2], b1[2][2];
      W2_LDA(a0, 1, 0); W2_LDB(b0, 1, 0);
      if (more) stgB(0, 0, kt2);
      PH_MID();
      W2_MFMA(0, 0, a0, b0);
      PH_END();
      W2_LDB(b1, 1, 1);
      if (more) stgA(1, 0, kt3);
      PH_MID();
      W2_MFMA(0, 1, a0, b1);
      PH_END();
      W2_LDA(a1, 1, 1);
      if (more) stgB(1, 1, kt3);
      PH_MID();
      W2_MFMA(1, 1, a1, b1);
      PH_END();
      W2_LDB(b0, 1, 0);
      if (more) stgA(1, 1, kt3);
      PH_MID();
      W2_MFMA(1, 0, a1, b0);
      __builtin_amdgcn_s_setprio(0);
      __builtin_amdgcn_sched_barrier(0);
      if (more) { asm volatile("s_waitcnt vmcnt(4)" ::: "memory"); }
      __builtin_amdgcn_s_barrier();
      __builtin_amdgcn_sched_barrier(0);
    }
  }

#pragma unroll
  for (int nt = 0; nt < 4; ++nt) {
    const long col = n0 + nt * 64 + wn * 16 + l16;
    const float bv = bias[col];
#pragma unroll
    for (int mt = 0; mt < 4; ++mt) {
#pragma unroll
      for (int r = 0; r < 4; ++r) {
        const long row = m0 + mt * 32 + wm * 16 + quad * 4 + r;
        const long idx = row * (long)N + col;
        Cout[idx] = acc[mt][nt][r] + bv + res[idx];
      }
    }
  }
}

// ---------------------------------------------------------------------------
// Flash attention fwd, S^T formulation, fixed-base softmax.
// v5 (T15-analog): QK(kt+1) hoisted ADJACENT to PV(kt) (no barrier between)
// so 32 independent MFMAs issue back-to-back; two static sacc sets alternate.
// V moves to a TRI-buffer (stage(kt+2) may not clobber V[kt] before PV(kt)):
// LDS = K dbuf 2x8KB + V tri 3x8KB = 40 KB -> still 4 blocks/CU.
// Hazards: stage(kt+2) writes K[kt&1] (dead: QK(kt) ran last iter, prev
// end-barrier) and V[(kt+2)%3] == V[kt-1] (dead: PV(kt-1), same barrier).
// vmcnt: stage=4 loads; at the wait, outstanding = {kt+1(4), kt+2(4)} ->
// vmcnt(4) == tile kt+1 landed.  Never drained in steady state.
// ---------------------------------------------------------------------------
__launch_bounds__(256, 4)
__global__ void attn_fwd(const unsigned short* __restrict__ qkv,
                         const unsigned short* __restrict__ vt,
                         unsigned short* __restrict__ outp) {
  // 40 KB: [K0 | K1 | V0 | V1 | V2], 8 KB (4096 ushorts) each
  __shared__ __align__(16) unsigned short lds[20480];

  const int tid = threadIdx.x;
  const int lane = tid & 63;
  const int wv = __builtin_amdgcn_readfirstlane(tid >> 6);  // 0..3
  const int quad = lane >> 4, l16 = lane & 15;

  const int id = blockIdx.y * 16 + blockIdx.x;   // grid (16, 64)
  const int xcd = id & 7, slot = id >> 3;        // slot 0..127
  const int bh = xcd * 8 + (slot >> 4);
  const int qt = slot & 15;
  const int b = bh >> 4, h = bh & 15;
  const long rowbase = (long)b * 2048;
  const int hoff = h * 64;

  const int rot0 = (quad + l16) & 7;
  const int rot1 = rot0 ^ 4;

  // ---- Q direct to registers (4 x 16B loads, one-time) ----
  bf16x8 bq[2][2];
#pragma unroll
  for (int s = 0; s < 2; ++s) {
    const long qrow = rowbase + qt * 128 + wv * 32 + s * 16 + l16;
    const unsigned short* qp = qkv + qrow * 3072 + hoff;
    bq[s][0] = *(const bf16x8*)(qp + quad * 8);
    bq[s][1] = *(const bf16x8*)(qp + (quad ^ 4) * 8);
  }
  __builtin_amdgcn_sched_barrier(0);   // keep bq loads issued before staging

  // staging constants: 512 chunks per 64-kv tile
  const int c0 = wv * 64 + lane;          // chunk 0..255
  const int r0 = c0 >> 3;                 // row 0..31
  const int ks = ((c0 & 7) - r0) & 7;
  const unsigned short* kptr = qkv + (rowbase + r0) * 3072 + 1024 + hoff + ks * 8;
  const unsigned short* vptr = vt + (long)bh * 131072 + (long)c0 * 8;

  auto stage = [&](int t) {   // tile t -> K[t&1], V[t%3]  (4 loads/wave)
    unsigned short* kdst = lds + ((t & 1) << 12) + wv * 512;
    unsigned short* vdst = lds + 8192 + ((t % 3) << 12) + wv * 512;
    const unsigned short* kp = kptr + (long)t * 64 * 3072;
    const unsigned short* vp = vptr + (long)t * 4096;
#pragma unroll
    for (int j = 0; j < 2; ++j) {
      async16(kp + (long)j * 32 * 3072, kdst + j * 2048);
      async16(vp + j * 2048, vdst + j * 2048);
    }
  };

  bf16x8 ones;
#pragma unroll
  for (int i = 0; i < 8; ++i) ones[i] = (short)0x3F80;

  f32x4 oacc[2][4], lacc[2];
#pragma unroll
  for (int s = 0; s < 2; ++s) {
    lacc[s] = (f32x4){0.f, 0.f, 0.f, 0.f};
#pragma unroll
    for (int i = 0; i < 4; ++i) oacc[s][i] = (f32x4){0.f, 0.f, 0.f, 0.f};
  }

  auto QK = [&](int t, f32x4 (&sx)[2][4]) {
    const unsigned short* Kb = lds + ((t & 1) << 12);
    __builtin_amdgcn_s_setprio(1);
#pragma unroll
    for (int tt = 0; tt < 4; ++tt) {
      const int ar = tt * 16 + l16;
      bf16x8 ak0 = *(const bf16x8*)(Kb + ar * 64 + rot0 * 8);
      bf16x8 ak1 = *(const bf16x8*)(Kb + ar * 64 + rot1 * 8);
#pragma unroll
      for (int s = 0; s < 2; ++s) {
        f32x4 z = (f32x4){0.f, 0.f, 0.f, 0.f};
        z = __builtin_amdgcn_mfma_f32_16x16x32_bf16(ak0, bq[s][0], z, 0, 0, 0);
        sx[s][tt] = __builtin_amdgcn_mfma_f32_16x16x32_bf16(ak1, bq[s][1], z, 0, 0, 0);
      }
    }
    __builtin_amdgcn_s_setprio(0);
  };

  auto SM = [&](f32x4 (&sx)[2][4], APU (&ap)[2][2]) {
#pragma unroll
    for (int s = 0; s < 2; ++s)
#pragma unroll
      for (int hf = 0; hf < 2; ++hf) {
#pragma unroll
        for (int tt = 0; tt < 2; ++tt) {
          const f32x4 sv = sx[s][hf * 2 + tt];
          const float p0 = __builtin_amdgcn_exp2f(sv[0]);
          const float p1 = __builtin_amdgcn_exp2f(sv[1]);
          const float p2 = __builtin_amdgcn_exp2f(sv[2]);
          const float p3 = __builtin_amdgcn_exp2f(sv[3]);
          ap[s][hf].u[tt * 2 + 0] = pk2(p0, p1);
          ap[s][hf].u[tt * 2 + 1] = pk2(p2, p3);
        }
        lacc[s] = __builtin_amdgcn_mfma_f32_16x16x32_bf16(ap[s][hf].v, ones,
                                                          lacc[s], 0, 0, 0);
      }
  };

  auto PV = [&](int t, APU (&ap)[2][2]) {
    const unsigned short* Vb = lds + 8192 + ((t % 3) << 12);
    __builtin_amdgcn_s_setprio(1);
#pragma unroll
    for (int hf = 0; hf < 2; ++hf) {
      const int vbase = (hf ? rot1 : rot0) * 8;
#pragma unroll
      for (int dt = 0; dt < 4; ++dt) {
        bf16x8 bv = *(const bf16x8*)(Vb + vbase + (dt * 16 + l16) * 64);
#pragma unroll
        for (int s = 0; s < 2; ++s)
          oacc[s][dt] = __builtin_amdgcn_mfma_f32_16x16x32_bf16(ap[s][hf].v, bv,
                                                                oacc[s][dt], 0, 0, 0);
      }
    }
    __builtin_amdgcn_s_setprio(0);
  };

  auto body = [&](int kt, f32x4 (&scur)[2][4], f32x4 (&snxt)[2][4], bool qknext) {
    const bool more = (kt + 2 < 32);
    if (more) stage(kt + 2);               // K[kt&1], V[(kt+2)%3]: both dead
    APU ap[2][2];
    SM(scur, ap);                          // VALU/trans covers staging issue
    if (more) { asm volatile("s_waitcnt vmcnt(4)" ::: "memory"); }  // kt+1 landed
    else      { asm volatile("s_waitcnt vmcnt(0)" ::: "memory"); }
    __builtin_amdgcn_s_barrier();          // kt+1 visible to all waves
    __builtin_amdgcn_sched_barrier(0);
    PV(kt, ap);                            // V[kt%3]
    if (qknext) QK(kt + 1, snxt);          // K[(kt+1)&1]; independent of PV
    __builtin_amdgcn_s_barrier();          // closes iter: K/V read-sets dead
    __builtin_amdgcn_sched_barrier(0);
  };

  // prologue: bq(4) + tile0(4) + tile1(4) in flight; vmcnt(4) = bq+tile0 done
  stage(0); stage(1);
  asm volatile("s_waitcnt vmcnt(4)" ::: "memory");
  __builtin_amdgcn_s_barrier();
  __builtin_amdgcn_sched_barrier(0);

  f32x4 sacc0[2][4], sacc1[2][4];
  QK(0, sacc0);                            // reads K[0]
  __builtin_amdgcn_s_barrier();            // all waves past QK(0) before stage(2)
  __builtin_amdgcn_sched_barrier(0);

  for (int it = 0; it < 16; ++it) {
    body(2 * it,     sacc0, sacc1, true);
    body(2 * it + 1, sacc1, sacc0, it < 15);
  }

  // epilogue: q-row = wv*32 + s*16 + quad*4 + r; lacc already in that layout
#pragma unroll
  for (int s = 0; s < 2; ++s) {
    float linv[4];
#pragma unroll
    for (int r = 0; r < 4; ++r) linv[r] = 1.f / lacc[s][r];
#pragma unroll
    for (int dt = 0; dt < 4; ++dt)
#pragma unroll
      for (int r = 0; r < 4; ++r) {
        const long row = rowbase + qt * 128 + wv * 32 + s * 16 + quad * 4 + r;
        outp[row * 1024 + hoff + dt * 16 + l16] = f2bf(oacc[s][dt][r] * linv[r]);
      }
  }
}

// ---------------------------------------------------------------------------
// launch
// ---------------------------------------------------------------------------
extern "C" void kernel_launch(void* const* d_in, const int* in_sizes, int n_in,
                              void* d_out, int out_size, void* d_ws, size_t ws_size,
                              hipStream_t stream) {
  (void)in_sizes; (void)n_in; (void)out_size; (void)ws_size;
  const float* x   = (const float*)d_in[0];
  const float* Wq  = (const float*)d_in[1];
  const float* Wk  = (const float*)d_in[2];
  const float* Wv  = (const float*)d_in[3];
  const float* Wo  = (const float*)d_in[4];
  const float* bo  = (const float*)d_in[5];
  const float* g1  = (const float*)d_in[6];
  const float* be1 = (const float*)d_in[7];
  const float* g2  = (const float*)d_in[8];
  const float* be2 = (const float*)d_in[9];
  const float* W1  = (const float*)d_in[10];
  const float* bf1 = (const float*)d_in[11];
  const float* W2  = (const float*)d_in[12];
  const float* bf2 = (const float*)d_in[13];

  static bool s_attr = false;
  if (!s_attr) {
    hipFuncSetAttribute(reinterpret_cast<const void*>(&gemm_w2),
                        hipFuncAttributeMaxDynamicSharedMemorySize, 98304);
    s_attr = true;
  }

  char* ws = (char*)d_ws;
  unsigned short* wqkv  = (unsigned short*)(ws);              // [3072,1024] bf16   6 MiB
  unsigned short* wo    = (unsigned short*)(ws + 6291456);    // [1024,1024]        2 MiB
  unsigned short* w1    = (unsigned short*)(ws + 8388608);    // [4096,1024]        8 MiB
  unsigned short* w2    = (unsigned short*)(ws + 16777216);   // [1024,4096]        8 MiB
  unsigned short* xn    = (unsigned short*)(ws + 25165824);   // [8192,1024]       16 MiB
  unsigned short* big   = (unsigned short*)(ws + 41943040);   // [8192,3072]       48 MiB
  unsigned short* vtg   = (unsigned short*)(ws + 92274688);   // [64][32][4096]    16 MiB
  unsigned short* attnb = (unsigned short*)(ws + 109051904);  // [8192,1024]       16 MiB
  float*          x1    = (float*)(ws + 125829120);           // [8192,1024] f32   32 MiB

  cvt_all<<<12288, 256, 0, stream>>>(Wq, Wk, Wv, Wo, W1, W2, wqkv);

  ln_fwd<<<8192, 256, 0, stream>>>(x, g1, be1, xn);
  gemm_bt<3><<<dim3(24, 64), 256, 0, stream>>>(xn, wqkv, big, nullptr, nullptr,
                                               vtg, 8192, 3072, 1024);
  attn_fwd<<<dim3(16, 64), 256, 0, stream>>>(big, vtg, attnb);
  gemm_bt<1><<<dim3(8, 64), 256, 0, stream>>>(attnb, wo, x1, bo, x,
                                              nullptr, 8192, 1024, 1024);
  ln_fwd<<<8192, 256, 0, stream>>>(x1, g2, be2, xn);
  gemm_bt<2><<<dim3(32, 64), 256, 0, stream>>>(xn, w1, big, bf1, nullptr,
                                               nullptr, 8192, 4096, 1024);
  gemm_w2<<<dim3(256), 512, 98304, stream>>>(big, w2, (float*)d_out, bf2, x1,
                                             8192, 1024, 4096);
}